// Round 1
// baseline (2418.700 us; speedup 1.0000x reference)
//
#include <hip/hip_runtime.h>
#include <math.h>

#define B_ 2
#define S_ 1024
#define E_ 1024
#define D_ 2048
#define H_ 8
#define KV_ 4
#define HD_ 256
#define NKEY (S_ + E_)
#define WINDOW_ 512
#define SCALE_ 0.0625f
#define CAP_ 50.0f
#define EPS_ 1e-6f

// ---------------- fp32 tiled GEMM: C(MxN) = A(MxK) @ W(KxN) ----------------
#define BM 64
#define BN 64
#define BK 16
__global__ __launch_bounds__(256) void gemm_f32(const float* __restrict__ A,
                                                const float* __restrict__ W,
                                                float* __restrict__ C,
                                                int M, int N, int K) {
    __shared__ float As[BM][BK + 1];   // +1 pad: avoid 4-way bank conflict on As[.][kk]
    __shared__ float Ws[BK][BN];
    const int tid = threadIdx.x;
    const int tx = tid & 15, ty = tid >> 4;
    const int row0 = blockIdx.y * BM, col0 = blockIdx.x * BN;
    float acc[4][4] = {};
    for (int k0 = 0; k0 < K; k0 += BK) {
#pragma unroll
        for (int i = 0; i < 4; ++i) {          // 64x16 A tile
            int idx = tid + i * 256;
            int r = idx >> 4, c = idx & 15;
            As[r][c] = A[(size_t)(row0 + r) * K + (k0 + c)];
        }
#pragma unroll
        for (int i = 0; i < 4; ++i) {          // 16x64 W tile
            int idx = tid + i * 256;
            int r = idx >> 6, c = idx & 63;
            Ws[r][c] = W[(size_t)(k0 + r) * N + (col0 + c)];
        }
        __syncthreads();
#pragma unroll
        for (int kk = 0; kk < BK; ++kk) {
            float a[4], w[4];
#pragma unroll
            for (int i = 0; i < 4; ++i) a[i] = As[ty * 4 + i][kk];
#pragma unroll
            for (int j = 0; j < 4; ++j) w[j] = Ws[kk][tx * 4 + j];
#pragma unroll
            for (int i = 0; i < 4; ++i)
#pragma unroll
                for (int j = 0; j < 4; ++j) acc[i][j] += a[i] * w[j];
        }
        __syncthreads();
    }
#pragma unroll
    for (int i = 0; i < 4; ++i)
#pragma unroll
        for (int j = 0; j < 4; ++j)
            C[(size_t)(row0 + ty * 4 + i) * N + (col0 + tx * 4 + j)] = acc[i][j];
}

// ---------------- RMSNorm (+optional RoPE), in place, one 256-elem row/block ---
__global__ __launch_bounds__(256) void rmsnorm_rope(float* __restrict__ x,
                                                    const float* __restrict__ w,
                                                    const float* __restrict__ cs,
                                                    const float* __restrict__ sn,
                                                    int nheads, int do_rope) {
    const int tid = threadIdx.x;
    const size_t base = (size_t)blockIdx.x * HD_;
    float v = x[base + tid];
    float ss = v * v;
#pragma unroll
    for (int off = 32; off; off >>= 1) ss += __shfl_down(ss, off);
    __shared__ float red[4];
    __shared__ float ybuf[HD_];
    const int lane = tid & 63, wvi = tid >> 6;
    if (lane == 0) red[wvi] = ss;
    __syncthreads();
    float tot = red[0] + red[1] + red[2] + red[3];
    float scale = rsqrtf(tot * (1.0f / HD_) + EPS_);
    float y = v * scale * (1.0f + w[tid]);
    if (do_rope) {                         // do_rope is uniform
        ybuf[tid] = y;
        __syncthreads();
        float rot = (tid < HD_ / 2) ? -ybuf[tid + HD_ / 2] : ybuf[tid - HD_ / 2];
        size_t coff = (size_t)(blockIdx.x / nheads) * HD_;   // (b*S+s)*HD
        y = y * cs[coff + tid] + rot * sn[coff + tid];
    }
    x[base + tid] = y;
}

// ---------------- segment ids from position_ids (serial scan per batch) -------
__global__ void seg_kernel(const int* __restrict__ pos, int* __restrict__ seg) {
    int b = threadIdx.x;
    if (b >= B_) return;
    int acc = 0, prev = 0;
    for (int s = 0; s < S_; ++s) {
        int p = pos[b * S_ + s];
        acc += (s == 0) || (p <= prev);
        seg[b * S_ + s] = acc;
        prev = p;
    }
}

// ---------------- flash attention, fp32, 16 q-rows x 16-key tiles -------------
#define QR 16
#define KT 16
__global__ __launch_bounds__(256) void attn_flash(
    const float* __restrict__ qb, const float* __restrict__ ksg,
    const float* __restrict__ vsg, const float* __restrict__ kcg,
    const float* __restrict__ vcg, const int* __restrict__ dm,
    const int* __restrict__ em, const int* __restrict__ seg,
    float* __restrict__ outp) {
    const int tid = threadIdx.x;
    const int nqt = S_ / QR;                   // 64
    const int qt = blockIdx.x % nqt;
    const int h = (blockIdx.x / nqt) % H_;
    const int b = blockIdx.x / (nqt * H_);
    const int kv = h / (H_ / KV_);
    const int s0 = qt * QR;

    __shared__ float qs[QR][HD_ + 4];          // pad 4: conflict-free + 16B aligned
    __shared__ float kst[KT][HD_ + 4];
    __shared__ float vst[KT][HD_];
    __shared__ float st[QR][KT + 4];           // row stride 80B, float4-aligned
    __shared__ float al[QR];
    __shared__ float ll[QR];

    for (int i = tid; i < QR * HD_; i += 256) {
        int r = i >> 8, d = i & 255;
        qs[r][d] = qb[(((size_t)b * S_ + (s0 + r)) * H_ + h) * HD_ + d];
    }
    float acc[QR];
#pragma unroll
    for (int r = 0; r < QR; ++r) acc[r] = 0.f;

    const int rd = tid >> 4;                   // dot-role: row
    const int kk = tid & 15;                   // dot-role: key-in-tile
    float m_r = -1e30f, l_r = 0.f;
    const int qpos = s0 + rd;
    const int seg_q = seg[b * S_ + qpos];
    __syncthreads();

    for (int kt0 = 0; kt0 < NKEY; kt0 += KT) {
        const bool self = (kt0 < S_);
        if (self) {
            if (kt0 > s0 + QR - 1) continue;                   // fully future (causal)
            if (s0 - (kt0 + KT - 1) >= WINDOW_) continue;      // fully outside window
        }
        for (int i = tid; i < KT * HD_; i += 256) {            // stage K,V tile
            int r = i >> 8, d = i & 255;
            int gk = kt0 + r;
            float kvv, vvv;
            if (self) {
                size_t o = (((size_t)b * S_ + gk) * KV_ + kv) * HD_ + d;
                kvv = ksg[o]; vvv = vsg[o];
            } else {
                size_t o = (((size_t)b * E_ + (gk - S_)) * KV_ + kv) * HD_ + d;
                kvv = kcg[o]; vvv = vcg[o];
            }
            kst[r][d] = kvv; vst[r][d] = vvv;
        }
        __syncthreads();

        float dot = 0.f;                                       // 256-MAC dot
#pragma unroll 8
        for (int d0 = 0; d0 < HD_; d0 += 4) {
            float4 qv = *(const float4*)&qs[rd][d0];
            float4 kq = *(const float4*)&kst[kk][d0];
            dot += qv.x * kq.x + qv.y * kq.y + qv.z * kq.z + qv.w * kq.w;
        }
        float sscore = CAP_ * tanhf(dot * (SCALE_ / CAP_));
        int gk = kt0 + kk;
        bool msk;
        if (self)
            msk = (dm[b * S_ + gk] != 0) && (gk <= qpos) &&
                  (seg[b * S_ + gk] == seg_q) && (qpos - gk < WINDOW_);
        else
            msk = (em[b * E_ + (gk - S_)] != 0);
        float s = msk ? sscore : -1e30f;

        float tmax = s;                                        // row-tile max (16 lanes)
#pragma unroll
        for (int off = 8; off; off >>= 1) tmax = fmaxf(tmax, __shfl_xor(tmax, off, 16));
        float newm = fmaxf(m_r, tmax);
        float alpha = __expf(m_r - newm);
        float p = (s <= -1e29f) ? 0.f : __expf(s - newm);      // explicit zero for masked
        float psum = p;
#pragma unroll
        for (int off = 8; off; off >>= 1) psum += __shfl_xor(psum, off, 16);
        l_r = l_r * alpha + psum;
        m_r = newm;
        st[rd][kk] = p;
        if (kk == 0) al[rd] = alpha;
        __syncthreads();

        // PV: thread owns output column d = tid for all QR rows
#pragma unroll
        for (int r = 0; r < QR; ++r) acc[r] *= al[r];
#pragma unroll
        for (int kk0 = 0; kk0 < KT; kk0 += 4) {
            float v0 = vst[kk0][tid], v1 = vst[kk0 + 1][tid];
            float v2 = vst[kk0 + 2][tid], v3 = vst[kk0 + 3][tid];
#pragma unroll
            for (int r = 0; r < QR; ++r) {
                float4 p4 = *(const float4*)&st[r][kk0];
                acc[r] += p4.x * v0 + p4.y * v1 + p4.z * v2 + p4.w * v3;
            }
        }
        __syncthreads();
    }
    if (kk == 0) ll[rd] = l_r;
    __syncthreads();
#pragma unroll
    for (int r = 0; r < QR; ++r) {
        float inv = 1.0f / ll[r];
        outp[(((size_t)b * S_ + (s0 + r)) * H_ + h) * HD_ + tid] = acc[r] * inv;
    }
}

extern "C" void kernel_launch(void* const* d_in, const int* in_sizes, int n_in,
                              void* d_out, int out_size, void* d_ws, size_t ws_size,
                              hipStream_t stream) {
    (void)in_sizes; (void)n_in; (void)out_size; (void)ws_size;
    const float* hs  = (const float*)d_in[0];
    const float* enc = (const float*)d_in[1];
    const float* cs  = (const float*)d_in[2];
    const float* sn  = (const float*)d_in[3];
    const float* wq  = (const float*)d_in[4];
    const float* wk  = (const float*)d_in[5];
    const float* wv  = (const float*)d_in[6];
    const float* wo  = (const float*)d_in[7];
    const float* qnw = (const float*)d_in[8];
    const float* knw = (const float*)d_in[9];
    const int* dm    = (const int*)d_in[10];
    const int* em    = (const int*)d_in[11];
    const int* pos   = (const int*)d_in[12];
    float* out = (float*)d_out;

    float* q_buf  = (float*)d_ws;                               // 4M floats
    float* kself  = q_buf  + (size_t)B_ * S_ * H_ * HD_;        // 2M
    float* vself  = kself  + (size_t)B_ * S_ * KV_ * HD_;       // 2M
    float* kcross = vself  + (size_t)B_ * S_ * KV_ * HD_;       // 2M
    float* vcross = kcross + (size_t)B_ * E_ * KV_ * HD_;       // 2M
    float* aout   = vcross + (size_t)B_ * E_ * KV_ * HD_;       // 4M
    int*   seg    = (int*)(aout + (size_t)B_ * S_ * H_ * HD_);  // B*S ints

    const int M = B_ * S_;
    gemm_f32<<<dim3((H_ * HD_) / BN, M / BM), 256, 0, stream>>>(hs, wq, q_buf, M, H_ * HD_, D_);
    gemm_f32<<<dim3((KV_ * HD_) / BN, M / BM), 256, 0, stream>>>(hs, wk, kself, M, KV_ * HD_, D_);
    gemm_f32<<<dim3((KV_ * HD_) / BN, M / BM), 256, 0, stream>>>(hs, wv, vself, M, KV_ * HD_, D_);
    gemm_f32<<<dim3((KV_ * HD_) / BN, M / BM), 256, 0, stream>>>(enc, wk, kcross, M, KV_ * HD_, D_);
    gemm_f32<<<dim3((KV_ * HD_) / BN, M / BM), 256, 0, stream>>>(enc, wv, vcross, M, KV_ * HD_, D_);

    rmsnorm_rope<<<B_ * S_ * H_, 256, 0, stream>>>(q_buf, qnw, cs, sn, H_, 1);
    rmsnorm_rope<<<B_ * S_ * KV_, 256, 0, stream>>>(kself, knw, cs, sn, KV_, 1);
    rmsnorm_rope<<<B_ * E_ * KV_, 256, 0, stream>>>(kcross, knw, cs, sn, KV_, 0);
    seg_kernel<<<1, 64, 0, stream>>>(pos, seg);

    attn_flash<<<B_ * H_ * (S_ / QR), 256, 0, stream>>>(q_buf, kself, vself, kcross, vcross,
                                                        dm, em, seg, aout);

    gemm_f32<<<dim3(D_ / BN, M / BM), 256, 0, stream>>>(aout, wo, out, M, D_, D_);
}

// Round 2
// 898.296 us; speedup vs baseline: 2.6925x; 2.6925x over previous
//
#include <hip/hip_runtime.h>
#include <math.h>

#define B_ 2
#define S_ 1024
#define E_ 1024
#define D_ 2048
#define H_ 8
#define KV_ 4
#define HD_ 256
#define NKEY (S_ + E_)
#define WINDOW_ 512
#define SCALE_ 0.0625f
#define CAP_ 50.0f
#define EPS_ 1e-6f

typedef __bf16 bf8_t __attribute__((ext_vector_type(8)));
typedef float fx4 __attribute__((ext_vector_type(4)));

#define MFMA16(a, b, c) __builtin_amdgcn_mfma_f32_16x16x32_bf16((a), (b), (c), 0, 0, 0)

typedef __attribute__((address_space(1))) unsigned int gas_u32;
typedef __attribute__((address_space(3))) unsigned int las_u32;
__device__ __forceinline__ void gl2lds16(const void* g, void* l) {
    __builtin_amdgcn_global_load_lds((const gas_u32*)g, (las_u32*)l, 16, 0, 0);
}

__device__ __forceinline__ float tanh_fast(float x) {   // saturation-safe
    float e = __expf(2.f * x);
    return 1.f - 2.f / (e + 1.f);
}

// ---------- elementwise split: fp32 -> bf16 hi + bf16 lo ----------
__global__ __launch_bounds__(256) void split2(const float* __restrict__ x,
                                              __bf16* __restrict__ hi,
                                              __bf16* __restrict__ lo, int n4) {
    int i = blockIdx.x * 256 + threadIdx.x;
    if (i >= n4) return;
    float4 v = ((const float4*)x)[i];
    union { __bf16 b[4]; unsigned long long u; } ph, pl;
    float vv[4] = {v.x, v.y, v.z, v.w};
#pragma unroll
    for (int r = 0; r < 4; ++r) {
        __bf16 h = (__bf16)vv[r];
        ph.b[r] = h;
        pl.b[r] = (__bf16)(vv[r] - (float)h);
    }
    *(unsigned long long*)&hi[(size_t)i * 4] = ph.u;
    *(unsigned long long*)&lo[(size_t)i * 4] = pl.u;
}

// ---------- transpose + split: W (KxN fp32) -> WT hi/lo (NxK bf16) ----------
__global__ __launch_bounds__(256) void tsplit(const float* __restrict__ W,
                                              __bf16* __restrict__ Th,
                                              __bf16* __restrict__ Tl, int K, int N) {
    __shared__ float tile[32][33];
    const int t = threadIdx.x, tx = t & 31, ty = t >> 5;       // ty 0..7
    const int k0 = blockIdx.x * 32, n0 = blockIdx.y * 32;
#pragma unroll
    for (int r = 0; r < 4; ++r)
        tile[ty + r * 8][tx] = W[(size_t)(k0 + ty + r * 8) * N + n0 + tx];
    __syncthreads();
#pragma unroll
    for (int r = 0; r < 4; ++r) {
        float v = tile[tx][ty + r * 8];
        __bf16 h = (__bf16)v;
        size_t o = (size_t)(n0 + ty + r * 8) * K + k0 + tx;
        Th[o] = h;
        Tl[o] = (__bf16)(v - (float)h);
    }
}

// ---------- split-bf16 MFMA GEMM: C(MxN) = (Ah+Al)(MxK) @ (Bh+Bl)^T ----------
// B given transposed (NxK). MODE 0: fp32 C row-major. MODE 1: bf16 C^T in
// v-transposed layout vt[b][kv][d][s] (N==1024, n=(kv,d), m=(b,s), S=1024).
template <int MODE>
__global__ __launch_bounds__(256) void gemm_split(
    const __bf16* __restrict__ Ah, const __bf16* __restrict__ Al,
    const __bf16* __restrict__ Bh, const __bf16* __restrict__ Bl,
    float* __restrict__ Cf, __bf16* __restrict__ Ct, int M, int N, int K) {
    __shared__ __bf16 As[2][128 * 32];
    __shared__ __bf16 Bs[2][128 * 32];
    const int tid = threadIdx.x, lane = tid & 63, wv = tid >> 6;
    const int l15 = lane & 15, lq = lane >> 4;
    const int row0 = blockIdx.y * 128, col0 = blockIdx.x * 128;
    const int wm = (wv >> 1) * 64, wn = (wv & 1) * 64;
    fx4 acc[4][4];
#pragma unroll
    for (int i = 0; i < 4; ++i)
#pragma unroll
        for (int j = 0; j < 4; ++j) acc[i][j] = (fx4){0.f, 0.f, 0.f, 0.f};

    for (int k0 = 0; k0 < K; k0 += 32) {
        __syncthreads();
#pragma unroll
        for (int s = 0; s < 2; ++s) {                      // 2 issues/wave/array
            int ia = wv * 2 + s;
            int c = ia * 64 + lane;                        // chunk 0..511
            int r = c >> 2, kc = c & 3;
            size_t ga = (size_t)(row0 + r) * K + k0 + kc * 8;
            size_t gb = (size_t)(col0 + r) * K + k0 + kc * 8;
            gl2lds16(Ah + ga, &As[0][ia * 512]);
            gl2lds16(Al + ga, &As[1][ia * 512]);
            gl2lds16(Bh + gb, &Bs[0][ia * 512]);
            gl2lds16(Bl + gb, &Bs[1][ia * 512]);
        }
        __syncthreads();
        bf8_t ah[4], al[4], bh[4], bl[4];
#pragma unroll
        for (int i = 0; i < 4; ++i) {
            int off = (wm + i * 16 + l15) * 32 + lq * 8;
            ah[i] = *(const bf8_t*)&As[0][off];
            al[i] = *(const bf8_t*)&As[1][off];
        }
#pragma unroll
        for (int j = 0; j < 4; ++j) {
            int off = (wn + j * 16 + l15) * 32 + lq * 8;
            bh[j] = *(const bf8_t*)&Bs[0][off];
            bl[j] = *(const bf8_t*)&Bs[1][off];
        }
#pragma unroll
        for (int i = 0; i < 4; ++i)
#pragma unroll
            for (int j = 0; j < 4; ++j) {
                acc[i][j] = MFMA16(ah[i], bh[j], acc[i][j]);
                acc[i][j] = MFMA16(ah[i], bl[j], acc[i][j]);
                acc[i][j] = MFMA16(al[i], bh[j], acc[i][j]);
            }
    }
#pragma unroll
    for (int i = 0; i < 4; ++i)
#pragma unroll
        for (int j = 0; j < 4; ++j) {
            int mb = row0 + wm + i * 16 + lq * 4;
            int n = col0 + wn + j * 16 + l15;
            if (MODE == 0) {
#pragma unroll
                for (int r = 0; r < 4; ++r)
                    Cf[(size_t)(mb + r) * N + n] = acc[i][j][r];
            } else {
                int b = mb >> 10, s = mb & 1023;
                int kv = n >> 8, d = n & 255;
                union { __bf16 b4[4]; unsigned long long u; } pk;
#pragma unroll
                for (int r = 0; r < 4; ++r) pk.b4[r] = (__bf16)acc[i][j][r];
                *(unsigned long long*)&Ct[(((size_t)b * KV_ + kv) * HD_ + d) * 1024 + s] = pk.u;
            }
        }
}

// ---------- RMSNorm (+optional RoPE): fp32 in, bf16 out ----------
__global__ __launch_bounds__(256) void rmsnorm_rope(const float* __restrict__ x,
                                                    __bf16* __restrict__ out,
                                                    const float* __restrict__ w,
                                                    const float* __restrict__ cs,
                                                    const float* __restrict__ sn,
                                                    int nheads, int do_rope) {
    const int tid = threadIdx.x;
    const size_t base = (size_t)blockIdx.x * HD_;
    float v = x[base + tid];
    float ss = v * v;
#pragma unroll
    for (int off = 32; off; off >>= 1) ss += __shfl_down(ss, off);
    __shared__ float red[4];
    __shared__ float ybuf[HD_];
    const int lane = tid & 63, wvi = tid >> 6;
    if (lane == 0) red[wvi] = ss;
    __syncthreads();
    float tot = red[0] + red[1] + red[2] + red[3];
    float scale = rsqrtf(tot * (1.0f / HD_) + EPS_);
    float y = v * scale * (1.0f + w[tid]);
    if (do_rope) {
        ybuf[tid] = y;
        __syncthreads();
        float rot = (tid < HD_ / 2) ? -ybuf[tid + HD_ / 2] : ybuf[tid - HD_ / 2];
        size_t coff = (size_t)(blockIdx.x / nheads) * HD_;
        y = y * cs[coff + tid] + rot * sn[coff + tid];
    }
    out[base + tid] = (__bf16)y;
}

// ---------- segment ids ----------
__global__ void seg_kernel(const int* __restrict__ pos, int* __restrict__ seg) {
    int b = threadIdx.x;
    if (b >= B_) return;
    int acc = 0, prev = 0;
    for (int s = 0; s < S_; ++s) {
        int p = pos[b * S_ + s];
        acc += (s == 0) || (p <= prev);
        seg[b * S_ + s] = acc;
        prev = p;
    }
}

// ---------- MFMA flash attention: 64 q-rows/block, 16/wave, 32-key tiles ----
__global__ __launch_bounds__(256) void attn_mfma(
    const __bf16* __restrict__ qb,   // [B][S][H][256]
    const __bf16* __restrict__ kb,   // [B][S][KV][256]
    const __bf16* __restrict__ kcb,  // [B][E][KV][256]
    const __bf16* __restrict__ vtS,  // [B][KV][256][S]
    const __bf16* __restrict__ vtC,  // [B][KV][256][E]
    const int* __restrict__ dm, const int* __restrict__ em,
    const int* __restrict__ seg,
    __bf16* __restrict__ aoutH, __bf16* __restrict__ aoutL) {
    __shared__ __bf16 Ks[32 * 256];
    __shared__ __bf16 Vs[256 * 32];
    __shared__ __bf16 Ps[4][16 * 32];
    const int tid = threadIdx.x, lane = tid & 63, wv = tid >> 6;
    const int l15 = lane & 15, lq = lane >> 4;
    const int qt = blockIdx.x & 15, h = (blockIdx.x >> 4) & 7, b = blockIdx.x >> 7;
    const int s0 = qt * 64, s0w = s0 + wv * 16;
    const int kv = h >> 1;                 // H/KV = 2

    bf8_t qf[8];
    {
        const __bf16* qrow = qb + (((size_t)b * S_ + s0w + l15) * H_ + h) * HD_;
#pragma unroll
        for (int f = 0; f < 8; ++f) qf[f] = *(const bf8_t*)(qrow + f * 32 + lq * 8);
    }
    const int rows0 = s0w + lq * 4;
    int4 segq4 = *(const int4*)(seg + b * S_ + rows0);
    int segq[4] = {segq4.x, segq4.y, segq4.z, segq4.w};
    float mR[4] = {-1e30f, -1e30f, -1e30f, -1e30f};
    float lR[4] = {0.f, 0.f, 0.f, 0.f};
    fx4 accO[16];
#pragma unroll
    for (int j = 0; j < 16; ++j) accO[j] = (fx4){0.f, 0.f, 0.f, 0.f};

    for (int kt0 = 0; kt0 < NKEY; kt0 += 32) {
        const bool self = kt0 < S_;
        if (self && kt0 >= s0 + 64) continue;             // fully future
        if (self && kt0 + 31 < s0 - (WINDOW_ - 1)) continue;  // fully below window
        __syncthreads();
#pragma unroll
        for (int s = 0; s < 4; ++s) {                     // stage K + V^T
            int ia = wv * 4 + s;
            int c = ia * 64 + lane;                       // 0..1023
            int kr = c >> 5, dc = c & 31;
            const __bf16* gk =
                self ? kb + (((size_t)b * S_ + kt0 + kr) * KV_ + kv) * HD_ + dc * 8
                     : kcb + (((size_t)b * E_ + kt0 - S_ + kr) * KV_ + kv) * HD_ + dc * 8;
            gl2lds16(gk, &Ks[ia * 512]);
            int dr = c >> 2, kc = c & 3;
            const __bf16* gv =
                self ? vtS + (((size_t)b * KV_ + kv) * HD_ + dr) * (size_t)S_ + kt0 + kc * 8
                     : vtC + (((size_t)b * KV_ + kv) * HD_ + dr) * (size_t)E_ + (kt0 - S_) + kc * 8;
            gl2lds16(gv, &Vs[ia * 512]);
        }
        __syncthreads();

        fx4 sc[2];
        sc[0] = (fx4){0.f, 0.f, 0.f, 0.f};
        sc[1] = (fx4){0.f, 0.f, 0.f, 0.f};
#pragma unroll
        for (int f = 0; f < 8; ++f) {
            sc[0] = MFMA16(qf[f], *(const bf8_t*)&Ks[l15 * 256 + f * 32 + lq * 8], sc[0]);
            sc[1] = MFMA16(qf[f], *(const bf8_t*)&Ks[(16 + l15) * 256 + f * 32 + lq * 8], sc[1]);
        }
        const int key0 = kt0 + l15, key1 = key0 + 16;
        bool kval0, kval1;
        int segk0 = 0, segk1 = 0;
        if (self) {
            kval0 = dm[b * S_ + key0] != 0; segk0 = seg[b * S_ + key0];
            kval1 = dm[b * S_ + key1] != 0; segk1 = seg[b * S_ + key1];
        } else {
            kval0 = em[b * E_ + key0 - S_] != 0;
            kval1 = em[b * E_ + key1 - S_] != 0;
        }
        float alphaR[4];
#pragma unroll
        for (int r = 0; r < 4; ++r) {
            int qpos = rows0 + r;
            float s0v = CAP_ * tanh_fast(sc[0][r] * (SCALE_ / CAP_));
            float s1v = CAP_ * tanh_fast(sc[1][r] * (SCALE_ / CAP_));
            bool val0, val1;
            if (self) {
                val0 = kval0 && segk0 == segq[r] && key0 <= qpos && qpos - key0 < WINDOW_;
                val1 = kval1 && segk1 == segq[r] && key1 <= qpos && qpos - key1 < WINDOW_;
            } else { val0 = kval0; val1 = kval1; }
            float z0 = val0 ? s0v : -1e30f, z1 = val1 ? s1v : -1e30f;
            float tm = fmaxf(z0, z1);
            tm = fmaxf(tm, __shfl_xor(tm, 1, 16));
            tm = fmaxf(tm, __shfl_xor(tm, 2, 16));
            tm = fmaxf(tm, __shfl_xor(tm, 4, 16));
            tm = fmaxf(tm, __shfl_xor(tm, 8, 16));
            float mn = fmaxf(mR[r], tm);
            float a = __expf(mR[r] - mn);
            float p0 = val0 ? __expf(s0v - mn) : 0.f;
            float p1 = val1 ? __expf(s1v - mn) : 0.f;
            float ps = p0 + p1;
            ps += __shfl_xor(ps, 1, 16);
            ps += __shfl_xor(ps, 2, 16);
            ps += __shfl_xor(ps, 4, 16);
            ps += __shfl_xor(ps, 8, 16);
            lR[r] = lR[r] * a + ps;
            mR[r] = mn;
            alphaR[r] = a;
            Ps[wv][(lq * 4 + r) * 32 + l15] = (__bf16)p0;
            Ps[wv][(lq * 4 + r) * 32 + 16 + l15] = (__bf16)p1;
        }
#pragma unroll
        for (int j = 0; j < 16; ++j)
#pragma unroll
            for (int r = 0; r < 4; ++r) accO[j][r] *= alphaR[r];
        bf8_t pf = *(const bf8_t*)&Ps[wv][l15 * 32 + lq * 8];
#pragma unroll
        for (int j = 0; j < 16; ++j) {
            bf8_t vb = *(const bf8_t*)&Vs[(j * 16 + l15) * 32 + lq * 8];
            accO[j] = MFMA16(pf, vb, accO[j]);
        }
    }
    float invR[4];
#pragma unroll
    for (int r = 0; r < 4; ++r) invR[r] = 1.0f / lR[r];
#pragma unroll
    for (int j = 0; j < 16; ++j)
#pragma unroll
        for (int r = 0; r < 4; ++r) {
            float o = accO[j][r] * invR[r];
            size_t idx = (size_t)(b * S_ + rows0 + r) * 2048 + h * 256 + j * 16 + l15;
            __bf16 hi = (__bf16)o;
            aoutH[idx] = hi;
            aoutL[idx] = (__bf16)(o - (float)hi);
        }
}

extern "C" void kernel_launch(void* const* d_in, const int* in_sizes, int n_in,
                              void* d_out, int out_size, void* d_ws, size_t ws_size,
                              hipStream_t stream) {
    (void)in_sizes; (void)n_in; (void)out_size; (void)ws_size;
    const float* hs  = (const float*)d_in[0];
    const float* enc = (const float*)d_in[1];
    const float* cs  = (const float*)d_in[2];
    const float* sn  = (const float*)d_in[3];
    const float* wq  = (const float*)d_in[4];
    const float* wk  = (const float*)d_in[5];
    const float* wv  = (const float*)d_in[6];
    const float* wo  = (const float*)d_in[7];
    const float* qnw = (const float*)d_in[8];
    const float* knw = (const float*)d_in[9];
    const int* dm    = (const int*)d_in[10];
    const int* em    = (const int*)d_in[11];
    const int* pos   = (const int*)d_in[12];
    float* out = (float*)d_out;

    char* ws = (char*)d_ws;
    const size_t MB = 1ull << 20;
    __bf16* hsH  = (__bf16*)(ws + 0 * MB);    // later: aoutH
    __bf16* hsL  = (__bf16*)(ws + 8 * MB);    // later: aoutL
    __bf16* encH = (__bf16*)(ws + 16 * MB);   // later: q_bf
    __bf16* encL = (__bf16*)(ws + 24 * MB);   // later: k_bf (4MB) + kc_bf (4MB)
    __bf16* wqTH = (__bf16*)(ws + 32 * MB);   // later: kcross_f32 (8MB)
    __bf16* wqTL = (__bf16*)(ws + 40 * MB);   // later: vtS (4MB) + vtC (4MB)
    __bf16* wkTH = (__bf16*)(ws + 48 * MB);
    __bf16* wkTL = (__bf16*)(ws + 52 * MB);
    __bf16* wvTH = (__bf16*)(ws + 56 * MB);
    __bf16* wvTL = (__bf16*)(ws + 60 * MB);
    float*  qf32 = (float*)(ws + 64 * MB);    // 16MB; later woTH/woTL
    float*  ksf  = (float*)(ws + 80 * MB);    // 8MB
    int*    seg  = (int*)(ws + 88 * MB);
    // aliases
    __bf16* aoutH = hsH; __bf16* aoutL = hsL;
    __bf16* q_bf = encH;
    __bf16* k_bf = encL; __bf16* kc_bf = (__bf16*)(ws + 28 * MB);
    float*  kcf  = (float*)(ws + 32 * MB);
    __bf16* vtS  = (__bf16*)(ws + 40 * MB);
    __bf16* vtC  = (__bf16*)(ws + 44 * MB);
    __bf16* woTH = (__bf16*)(ws + 64 * MB);
    __bf16* woTL = (__bf16*)(ws + 72 * MB);

    const int M = B_ * S_;                    // 2048

    split2<<<(M * D_ / 4 + 255) / 256, 256, 0, stream>>>(hs, hsH, hsL, M * D_ / 4);
    split2<<<(M * D_ / 4 + 255) / 256, 256, 0, stream>>>(enc, encH, encL, M * D_ / 4);
    tsplit<<<dim3(D_ / 32, 2048 / 32), 256, 0, stream>>>(wq, wqTH, wqTL, D_, 2048);
    tsplit<<<dim3(D_ / 32, 1024 / 32), 256, 0, stream>>>(wk, wkTH, wkTL, D_, 1024);
    tsplit<<<dim3(D_ / 32, 1024 / 32), 256, 0, stream>>>(wv, wvTH, wvTL, D_, 1024);

    gemm_split<0><<<dim3(2048 / 128, M / 128), 256, 0, stream>>>(hsH, hsL, wqTH, wqTL, qf32, nullptr, M, 2048, D_);
    gemm_split<0><<<dim3(1024 / 128, M / 128), 256, 0, stream>>>(hsH, hsL, wkTH, wkTL, ksf, nullptr, M, 1024, D_);
    gemm_split<1><<<dim3(1024 / 128, M / 128), 256, 0, stream>>>(hsH, hsL, wvTH, wvTL, nullptr, vtS, M, 1024, D_);
    gemm_split<0><<<dim3(1024 / 128, M / 128), 256, 0, stream>>>(encH, encL, wkTH, wkTL, kcf, nullptr, M, 1024, D_);
    gemm_split<1><<<dim3(1024 / 128, M / 128), 256, 0, stream>>>(encH, encL, wvTH, wvTL, nullptr, vtC, M, 1024, D_);

    rmsnorm_rope<<<B_ * S_ * H_, 256, 0, stream>>>(qf32, q_bf, qnw, cs, sn, H_, 1);
    rmsnorm_rope<<<B_ * S_ * KV_, 256, 0, stream>>>(ksf, k_bf, knw, cs, sn, KV_, 1);
    rmsnorm_rope<<<B_ * E_ * KV_, 256, 0, stream>>>(kcf, kc_bf, knw, cs, sn, KV_, 0);
    seg_kernel<<<1, 64, 0, stream>>>(pos, seg);

    tsplit<<<dim3(2048 / 32, D_ / 32), 256, 0, stream>>>(wo, woTH, woTL, 2048, D_);

    attn_mfma<<<B_ * H_ * (S_ / 64), 256, 0, stream>>>(q_bf, k_bf, kc_bf, vtS, vtC,
                                                       dm, em, seg, aoutH, aoutL);

    gemm_split<0><<<dim3(D_ / 128, M / 128), 256, 0, stream>>>(aoutH, aoutL, woTH, woTL, out, nullptr, M, D_, 2048);
}

// Round 3
// 681.918 us; speedup vs baseline: 3.5469x; 1.3173x over previous
//
#include <hip/hip_runtime.h>
#include <math.h>

#define B_ 2
#define S_ 1024
#define E_ 1024
#define D_ 2048
#define H_ 8
#define KV_ 4
#define HD_ 256
#define WINDOW_ 512u
#define SCALE_ 0.0625f
#define CAP_ 50.0f
#define EPS_ 1e-6f
#define CROSS_OK (-7)
#define KINV (-2147483647 - 1)

typedef __bf16 bf8_t __attribute__((ext_vector_type(8)));
typedef float fx4 __attribute__((ext_vector_type(4)));
#define MFMA16(a, b, c) __builtin_amdgcn_mfma_f32_16x16x32_bf16((a), (b), (c), 0, 0, 0)

typedef __attribute__((address_space(1))) unsigned int gas_u32;
typedef __attribute__((address_space(3))) unsigned int las_u32;
__device__ __forceinline__ void gl2lds16(const void* g, void* l) {
    __builtin_amdgcn_global_load_lds((const gas_u32*)g, (las_u32*)l, 16, 0, 0);
}

union U4 { __bf16 b[4]; unsigned long long u; };

// p = exp(50*tanh(dot*SCALE/50) - 50) = exp(-100/(exp(dot*2*SCALE/50)+1))
__device__ __forceinline__ float pexp(float dot) {
    float e = __expf(dot * (2.0f * SCALE_ / CAP_));
    return __expf(-(2.0f * CAP_) / (e + 1.0f));
}

// ---------------- fp32 -> bf16 (hi only) ----------------
__global__ __launch_bounds__(256) void tobf16(const float* __restrict__ x,
                                              __bf16* __restrict__ y, int n4) {
    int i = blockIdx.x * 256 + threadIdx.x;
    if (i >= n4) return;
    float4 v = ((const float4*)x)[i];
    U4 p;
    p.b[0] = (__bf16)v.x; p.b[1] = (__bf16)v.y;
    p.b[2] = (__bf16)v.z; p.b[3] = (__bf16)v.w;
    *(unsigned long long*)&y[(size_t)i * 4] = p.u;
}

// ---------------- transpose + split: W (KxN fp32) -> WT hi/lo (NxK bf16) -----
__global__ __launch_bounds__(256) void tsplit(const float* __restrict__ W,
                                              __bf16* __restrict__ Th,
                                              __bf16* __restrict__ Tl, int K, int N) {
    __shared__ float tile[32][33];
    const int t = threadIdx.x, tx = t & 31, ty = t >> 5;
    const int k0 = blockIdx.x * 32, n0 = blockIdx.y * 32;
#pragma unroll
    for (int r = 0; r < 4; ++r)
        tile[ty + r * 8][tx] = W[(size_t)(k0 + ty + r * 8) * N + n0 + tx];
    __syncthreads();
#pragma unroll
    for (int r = 0; r < 4; ++r) {
        float v = tile[tx][ty + r * 8];
        __bf16 h = (__bf16)v;
        size_t o = (size_t)(n0 + ty + r * 8) * K + k0 + tx;
        Th[o] = h;
        Tl[o] = (__bf16)(v - (float)h);
    }
}

// ---------------- shared GEMM core: 128x128 tile, BK=32, gl2lds staging ------
template <int NPASS>
__device__ __forceinline__ void gemm_core(
    const __bf16* __restrict__ Ah, const __bf16* __restrict__ Al,
    const __bf16* __restrict__ Bh, const __bf16* __restrict__ Bl,
    int row0, int col0, int K,
    __bf16* As0, __bf16* As1, __bf16* Bs0, __bf16* Bs1, fx4 (&acc)[4][4]) {
    const int tid = threadIdx.x, lane = tid & 63, wv = tid >> 6;
    const int l15 = lane & 15, lq = lane >> 4;
    const int wm = (wv >> 1) * 64, wn = (wv & 1) * 64;
    for (int k0 = 0; k0 < K; k0 += 32) {
        __syncthreads();
#pragma unroll
        for (int s = 0; s < 2; ++s) {
            int ch = (wv * 2 + s) * 64 + lane;       // 0..511
            int r = ch >> 2, kc = ch & 3;
            size_t ga = (size_t)(row0 + r) * K + k0 + kc * 8;
            size_t gb = (size_t)(col0 + r) * K + k0 + kc * 8;
            gl2lds16(Ah + ga, As0 + ch * 8);
            if (NPASS == 3) gl2lds16(Al + ga, As1 + ch * 8);
            gl2lds16(Bh + gb, Bs0 + ch * 8);
            gl2lds16(Bl + gb, Bs1 + ch * 8);
        }
        __syncthreads();
        bf8_t ah[4], al[4], bh[4], bl[4];
#pragma unroll
        for (int i = 0; i < 4; ++i) {
            int off = (wm + i * 16 + l15) * 32 + lq * 8;
            ah[i] = *(const bf8_t*)(As0 + off);
            if (NPASS == 3) al[i] = *(const bf8_t*)(As1 + off);
        }
#pragma unroll
        for (int j = 0; j < 4; ++j) {
            int off = (wn + j * 16 + l15) * 32 + lq * 8;
            bh[j] = *(const bf8_t*)(Bs0 + off);
            bl[j] = *(const bf8_t*)(Bs1 + off);
        }
#pragma unroll
        for (int i = 0; i < 4; ++i)
#pragma unroll
            for (int j = 0; j < 4; ++j) {
                acc[i][j] = MFMA16(ah[i], bh[j], acc[i][j]);
                acc[i][j] = MFMA16(ah[i], bl[j], acc[i][j]);
                if (NPASS == 3) acc[i][j] = MFMA16(al[i], bh[j], acc[i][j]);
            }
    }
}

// ---------------- fused projection GEMM (hs->q,k,v ; enc->kc,vc) ------------
__global__ __launch_bounds__(256) void gemm_proj(
    const __bf16* __restrict__ hsb, const __bf16* __restrict__ encb,
    const __bf16* __restrict__ BTh, const __bf16* __restrict__ BTl,
    float* __restrict__ qf32, float* __restrict__ ksf, float* __restrict__ kcf,
    __bf16* __restrict__ vtS, __bf16* __restrict__ vtC) {
    __shared__ __bf16 As0[4096], Bs0[4096], Bs1[4096];
    const int bx = blockIdx.x, row0 = blockIdx.y * 128;
    const __bf16* A;
    float* Ck; __bf16* Cv; int col0;
    if (bx < 32) { A = hsb;  col0 = bx * 128;               Ck = ksf; Cv = vtS; }
    else         { A = encb; col0 = (bx - 32) * 128 + 2048; Ck = kcf; Cv = vtC; }
    fx4 acc[4][4];
#pragma unroll
    for (int i = 0; i < 4; ++i)
#pragma unroll
        for (int j = 0; j < 4; ++j) acc[i][j] = (fx4){0.f, 0.f, 0.f, 0.f};
    gemm_core<2>(A, nullptr, BTh, BTl, row0, col0, D_, As0, nullptr, Bs0, Bs1, acc);

    const int tid = threadIdx.x, lane = tid & 63, wv = tid >> 6;
    const int l15 = lane & 15, lq = lane >> 4;
    const int wm = (wv >> 1) * 64, wn = (wv & 1) * 64;
    const int mode = (col0 < 2048) ? 0 : (col0 < 3072 ? 1 : 2);
#pragma unroll
    for (int i = 0; i < 4; ++i)
#pragma unroll
        for (int j = 0; j < 4; ++j) {
            int mb = row0 + wm + i * 16 + lq * 4;
            int n = col0 + wn + j * 16 + l15;
            if (mode == 0) {
#pragma unroll
                for (int r = 0; r < 4; ++r)
                    qf32[(size_t)(mb + r) * 2048 + n] = acc[i][j][r];
            } else if (mode == 1) {
                int nk = n - 2048;
#pragma unroll
                for (int r = 0; r < 4; ++r)
                    Ck[(size_t)(mb + r) * 1024 + nk] = acc[i][j][r];
            } else {
                int nv = n - 3072;
                int b = mb >> 10, s = mb & 1023;
                int kv = nv >> 8, d = nv & 255;
                U4 pk;
#pragma unroll
                for (int r = 0; r < 4; ++r) pk.b[r] = (__bf16)acc[i][j][r];
                *(unsigned long long*)&Cv[((size_t)(b * KV_ + kv) * HD_ + d) * 1024 + s] = pk.u;
            }
        }
}

// ---------------- output GEMM (3-term split) ----------------
__global__ __launch_bounds__(256) void gemm_out(
    const __bf16* __restrict__ Ah, const __bf16* __restrict__ Al,
    const __bf16* __restrict__ Bh, const __bf16* __restrict__ Bl,
    float* __restrict__ C) {
    __shared__ __bf16 As0[4096], As1[4096], Bs0[4096], Bs1[4096];
    const int row0 = blockIdx.y * 128, col0 = blockIdx.x * 128;
    fx4 acc[4][4];
#pragma unroll
    for (int i = 0; i < 4; ++i)
#pragma unroll
        for (int j = 0; j < 4; ++j) acc[i][j] = (fx4){0.f, 0.f, 0.f, 0.f};
    gemm_core<3>(Ah, Al, Bh, Bl, row0, col0, 2048, As0, As1, Bs0, Bs1, acc);
    const int tid = threadIdx.x, lane = tid & 63, wv = tid >> 6;
    const int l15 = lane & 15, lq = lane >> 4;
    const int wm = (wv >> 1) * 64, wn = (wv & 1) * 64;
#pragma unroll
    for (int i = 0; i < 4; ++i)
#pragma unroll
        for (int j = 0; j < 4; ++j) {
            int mb = row0 + wm + i * 16 + lq * 4;
            int n = col0 + wn + j * 16 + l15;
#pragma unroll
            for (int r = 0; r < 4; ++r)
                C[(size_t)(mb + r) * 2048 + n] = acc[i][j][r];
        }
}

// ---------------- RMSNorm (+optional RoPE): fp32 in, bf16 out ---------------
__global__ __launch_bounds__(256) void rmsnorm_rope(const float* __restrict__ x,
                                                    __bf16* __restrict__ out,
                                                    const float* __restrict__ w,
                                                    const float* __restrict__ cs,
                                                    const float* __restrict__ sn,
                                                    int nheads, int do_rope, int trans) {
    const int tid = threadIdx.x;
    const size_t base = (size_t)blockIdx.x * HD_;
    float v = x[base + tid];
    float ss = v * v;
#pragma unroll
    for (int off = 32; off; off >>= 1) ss += __shfl_down(ss, off);
    __shared__ float red[4];
    __shared__ float ybuf[HD_];
    const int lane = tid & 63, wvi = tid >> 6;
    if (lane == 0) red[wvi] = ss;
    __syncthreads();
    float tot = red[0] + red[1] + red[2] + red[3];
    float scale = rsqrtf(tot * (1.0f / HD_) + EPS_);
    float y = v * scale * (1.0f + w[tid]);
    const int m = blockIdx.x / nheads;
    if (do_rope) {
        ybuf[tid] = y;
        __syncthreads();
        float rot = (tid < HD_ / 2) ? -ybuf[tid + HD_ / 2] : ybuf[tid - HD_ / 2];
        size_t coff = (size_t)m * HD_;
        y = y * cs[coff + tid] + rot * sn[coff + tid];
    }
    size_t oidx;
    if (trans) {
        int hh = blockIdx.x % nheads;
        int b = m >> 10, s = m & 1023;
        oidx = ((size_t)(b * nheads + hh) * 1024 + s) * HD_ + tid;
    } else {
        oidx = base + tid;
    }
    out[oidx] = (__bf16)y;
}

// ---------------- segment scan + key info ----------------
__global__ void segscan(const int* __restrict__ pos, const int* __restrict__ dm,
                        const int* __restrict__ em, int* __restrict__ seg,
                        int* __restrict__ ki) {
    const int b = blockIdx.x, s = threadIdx.x;
    __shared__ int sh[1024];
    int p = pos[b * S_ + s];
    int r = (s == 0) ? 1 : (p <= pos[b * S_ + s - 1] ? 1 : 0);
    sh[s] = r;
    __syncthreads();
    for (int off = 1; off < 1024; off <<= 1) {
        int v = sh[s];
        int u = (s >= off) ? sh[s - off] : 0;
        __syncthreads();
        sh[s] = v + u;
        __syncthreads();
    }
    int sv = sh[s];
    seg[b * S_ + s] = sv;
    ki[b * 2048 + s] = dm[b * S_ + s] ? sv : KINV;
    ki[b * 2048 + 1024 + s] = em[b * E_ + s] ? CROSS_OK : KINV;
}

// ---------------- attention partial: 1 wave / block, no barriers ------------
// blockIdx: bit0 = cross-half, then qt(64) | h(8) | b(2). 16 q-rows per wave.
__global__ __launch_bounds__(64, 2) void attn_part(
    const __bf16* __restrict__ qb,   // [B][S][H][256]
    const __bf16* __restrict__ kb,   // [B][KV][S][256]
    const __bf16* __restrict__ kcb,  // [B][KV][E][256]
    const __bf16* __restrict__ vtS,  // [B][KV][256][S]
    const __bf16* __restrict__ vtC,  // [B][KV][256][E]
    const int* __restrict__ seg, const int* __restrict__ ki,
    float* __restrict__ oS, float* __restrict__ oC,
    float* __restrict__ lS, float* __restrict__ lC) {
    const int lane = threadIdx.x, l15 = lane & 15, lq = lane >> 4;
    int idx = blockIdx.x;
    const int cross = idx & 1; idx >>= 1;
    const int qt = idx & 63, h = (idx >> 6) & 7, b = idx >> 9;
    const int s0 = qt * 16, kv = h >> 1;
    __shared__ __bf16 Ps[16 * 40];               // padded stride 40

    bf8_t qf[8];
    const __bf16* qrow = qb + ((size_t)(b * S_ + s0 + l15) * H_ + h) * HD_;
#pragma unroll
    for (int f = 0; f < 8; ++f) qf[f] = *(const bf8_t*)(qrow + f * 32 + lq * 8);
    const int qpos = s0 + l15;
    const int segq = seg[b * S_ + qpos];
    const int tgt = cross ? CROSS_OK : segq;

    fx4 accO[16];
#pragma unroll
    for (int j = 0; j < 16; ++j) accO[j] = (fx4){0.f, 0.f, 0.f, 0.f};
    float lsum = 0.f;

    int kt_lo, kt_hi;
    const __bf16 *Kb, *Vb;
    const int* kio;
    if (!cross) {
        int lo = s0 - 511; if (lo < 0) lo = 0;
        kt_lo = lo & ~31; kt_hi = s0 + 15;
        Kb = kb + (size_t)(b * KV_ + kv) * 1024 * 256;
        Vb = vtS + (size_t)(b * KV_ + kv) * 256 * 1024;
        kio = ki + b * 2048;
    } else {
        kt_lo = 0; kt_hi = 1023;
        Kb = kcb + (size_t)(b * KV_ + kv) * 1024 * 256;
        Vb = vtC + (size_t)(b * KV_ + kv) * 256 * 1024;
        kio = ki + b * 2048 + 1024;
    }

    for (int kt0 = kt_lo; kt0 <= kt_hi; kt0 += 32) {
        const __bf16* kr0 = Kb + (size_t)(kt0 + l15) * 256;
        bf8_t kf0[8], kf1[8];
#pragma unroll
        for (int f = 0; f < 8; ++f) kf0[f] = *(const bf8_t*)(kr0 + f * 32 + lq * 8);
#pragma unroll
        for (int f = 0; f < 8; ++f) kf1[f] = *(const bf8_t*)(kr0 + 16 * 256 + f * 32 + lq * 8);
        fx4 sc0 = (fx4){0.f, 0.f, 0.f, 0.f}, sc1 = (fx4){0.f, 0.f, 0.f, 0.f};
#pragma unroll
        for (int f = 0; f < 8; ++f) sc0 = MFMA16(kf0[f], qf[f], sc0);
#pragma unroll
        for (int f = 0; f < 8; ++f) sc1 = MFMA16(kf1[f], qf[f], sc1);
        // lane: q-row = l15; keys kt0 + lq*4 + r (+16)
        int4 ki0 = *(const int4*)(kio + kt0 + lq * 4);
        int4 ki1 = *(const int4*)(kio + kt0 + 16 + lq * 4);
        int ka0[4] = {ki0.x, ki0.y, ki0.z, ki0.w};
        int ka1[4] = {ki1.x, ki1.y, ki1.z, ki1.w};
        U4 p0, p1;
#pragma unroll
        for (int r = 0; r < 4; ++r) {
            int key0 = kt0 + lq * 4 + r;
            float e0 = pexp(sc0[r]);
            float e1 = pexp(sc1[r]);
            bool ok0 = (ka0[r] == tgt) && (cross || (unsigned)(qpos - key0) < WINDOW_);
            bool ok1 = (ka1[r] == tgt) && (cross || (unsigned)(qpos - key0 - 16) < WINDOW_);
            float v0 = ok0 ? e0 : 0.f;
            float v1 = ok1 ? e1 : 0.f;
            lsum += v0 + v1;
            p0.b[r] = (__bf16)v0;
            p1.b[r] = (__bf16)v1;
        }
        *(unsigned long long*)&Ps[l15 * 40 + lq * 4] = p0.u;
        *(unsigned long long*)&Ps[l15 * 40 + 16 + lq * 4] = p1.u;
        bf8_t pf = *(const bf8_t*)&Ps[l15 * 40 + lq * 8];
#pragma unroll
        for (int j = 0; j < 16; ++j) {
            bf8_t vb = *(const bf8_t*)(Vb + (size_t)(j * 16 + l15) * 1024 + kt0 + lq * 8);
            accO[j] = MFMA16(pf, vb, accO[j]);
        }
    }
    lsum += __shfl_xor(lsum, 16);
    lsum += __shfl_xor(lsum, 32);
    float* oP = cross ? oC : oS;
    float* lP = cross ? lC : lS;
#pragma unroll
    for (int j = 0; j < 16; ++j)
#pragma unroll
        for (int r = 0; r < 4; ++r)
            oP[(size_t)(b * S_ + s0 + lq * 4 + r) * 2048 + h * 256 + j * 16 + l15] = accO[j][r];
    if (lane < 16) lP[(size_t)(b * H_ + h) * 1024 + s0 + l15] = lsum;
}

// ---------------- merge self+cross partials, normalize, split-bf16 ----------
__global__ __launch_bounds__(256) void merge_attn(
    const float* __restrict__ oS, const float* __restrict__ oC,
    const float* __restrict__ lS, const float* __restrict__ lC,
    __bf16* __restrict__ aH, __bf16* __restrict__ aL) {
    int i = blockIdx.x * 256 + threadIdx.x;       // float4 idx over [2048][512]
    float4 a = ((const float4*)oS)[i];
    float4 c = ((const float4*)oC)[i];
    int m = i >> 9;
    int h = (i >> 6) & 7;
    int b = m >> 10, s = m & 1023;
    size_t li = (size_t)(b * H_ + h) * 1024 + s;
    float inv = 1.0f / (lS[li] + lC[li]);
    float o[4] = {(a.x + c.x) * inv, (a.y + c.y) * inv, (a.z + c.z) * inv, (a.w + c.w) * inv};
    U4 ph, pl;
#pragma unroll
    for (int r = 0; r < 4; ++r) {
        __bf16 hi = (__bf16)o[r];
        ph.b[r] = hi;
        pl.b[r] = (__bf16)(o[r] - (float)hi);
    }
    *(unsigned long long*)&aH[(size_t)i * 4] = ph.u;
    *(unsigned long long*)&aL[(size_t)i * 4] = pl.u;
}

extern "C" void kernel_launch(void* const* d_in, const int* in_sizes, int n_in,
                              void* d_out, int out_size, void* d_ws, size_t ws_size,
                              hipStream_t stream) {
    (void)in_sizes; (void)n_in; (void)out_size; (void)ws_size;
    const float* hs  = (const float*)d_in[0];
    const float* enc = (const float*)d_in[1];
    const float* cs  = (const float*)d_in[2];
    const float* sn  = (const float*)d_in[3];
    const float* wq  = (const float*)d_in[4];
    const float* wk  = (const float*)d_in[5];
    const float* wv  = (const float*)d_in[6];
    const float* wo  = (const float*)d_in[7];
    const float* qnw = (const float*)d_in[8];
    const float* knw = (const float*)d_in[9];
    const int* dm    = (const int*)d_in[10];
    const int* em    = (const int*)d_in[11];
    const int* pos   = (const int*)d_in[12];
    float* out = (float*)d_out;

    char* ws = (char*)d_ws;
    const size_t MB = 1ull << 20;
    __bf16* hs_bf   = (__bf16*)(ws + 0 * MB);    // 8 MB   (dead after gemm_proj)
    __bf16* enc_bf  = (__bf16*)(ws + 8 * MB);    // 8 MB   (dead after gemm_proj)
    __bf16* wqkvTH  = (__bf16*)(ws + 16 * MB);   // 16 MB  (dead after gemm_proj)
    __bf16* wqkvTL  = (__bf16*)(ws + 32 * MB);   // 16 MB
    __bf16* woTH    = (__bf16*)(ws + 48 * MB);   // 8 MB
    __bf16* woTL    = (__bf16*)(ws + 56 * MB);   // 8 MB
    float*  qf32    = (float*)(ws + 64 * MB);    // 16 MB  (dead after rmsnorm q)
    float*  ksf     = (float*)(ws + 80 * MB);    // 8 MB   (dead after rmsnorm k)
    float*  kcf     = (float*)(ws + 88 * MB);    // 8 MB   (dead after rmsnorm kc)
    __bf16* k_bf    = (__bf16*)(ws + 104 * MB);  // 4 MB   [B][KV][S][256]
    __bf16* kc_bf   = (__bf16*)(ws + 108 * MB);  // 4 MB
    __bf16* vtS     = (__bf16*)(ws + 112 * MB);  // 4 MB   [B][KV][256][S]
    __bf16* vtC     = (__bf16*)(ws + 116 * MB);  // 4 MB
    int*    seg     = (int*)(ws + 120 * MB);     // 8 KB
    int*    kinfo   = (int*)(ws + 121 * MB);     // 16 KB
    float*  lS      = (float*)(ws + 122 * MB);   // 64 KB
    float*  lC      = (float*)(ws + 123 * MB);   // 64 KB
    __bf16* q_bf    = (__bf16*)(ws + 124 * MB);  // 8 MB   [B][S][H][256]
    // reuse of dead regions:
    float*  oS      = (float*)(ws + 64 * MB);    // 16.78 MB over qf32/ksf
    float*  oC      = (float*)(ws + 81 * MB);    // 16.78 MB over kcf tail
    __bf16* aoutH   = (__bf16*)(ws + 0 * MB);    // 8.39 MB over hs_bf
    __bf16* aoutL   = (__bf16*)(ws + 9 * MB);    // 8.39 MB over enc_bf/wqkvTH

    const int M = B_ * S_;   // 2048

    tobf16<<<4096, 256, 0, stream>>>(hs, hs_bf, M * D_ / 4);
    tobf16<<<4096, 256, 0, stream>>>(enc, enc_bf, M * D_ / 4);
    tsplit<<<dim3(64, 64), 256, 0, stream>>>(wq, wqkvTH, wqkvTL, D_, 2048);
    tsplit<<<dim3(64, 32), 256, 0, stream>>>(wk, wqkvTH + (size_t)2048 * 2048,
                                             wqkvTL + (size_t)2048 * 2048, D_, 1024);
    tsplit<<<dim3(64, 32), 256, 0, stream>>>(wv, wqkvTH + (size_t)3072 * 2048,
                                             wqkvTL + (size_t)3072 * 2048, D_, 1024);
    tsplit<<<dim3(64, 64), 256, 0, stream>>>(wo, woTH, woTL, 2048, D_);

    gemm_proj<<<dim3(48, 16), 256, 0, stream>>>(hs_bf, enc_bf, wqkvTH, wqkvTL,
                                                qf32, ksf, kcf, vtS, vtC);

    rmsnorm_rope<<<16384, 256, 0, stream>>>(qf32, q_bf, qnw, cs, sn, H_, 1, 0);
    rmsnorm_rope<<<8192, 256, 0, stream>>>(ksf, k_bf, knw, cs, sn, KV_, 1, 1);
    rmsnorm_rope<<<8192, 256, 0, stream>>>(kcf, kc_bf, knw, cs, sn, KV_, 0, 1);
    segscan<<<B_, 1024, 0, stream>>>(pos, dm, em, seg, kinfo);

    attn_part<<<2048, 64, 0, stream>>>(q_bf, k_bf, kc_bf, vtS, vtC, seg, kinfo,
                                       oS, oC, lS, lC);
    merge_attn<<<4096, 256, 0, stream>>>(oS, oC, lS, lC, aoutH, aoutL);

    gemm_out<<<dim3(16, 16), 256, 0, stream>>>(aoutH, aoutL, woTH, woTL, out);
}

// Round 4
// 644.723 us; speedup vs baseline: 3.7515x; 1.0577x over previous
//
#include <hip/hip_runtime.h>
#include <math.h>

#define B_ 2
#define S_ 1024
#define E_ 1024
#define D_ 2048
#define H_ 8
#define KV_ 4
#define HD_ 256
#define WINDOW_ 512u
#define SCALE_ 0.0625f
#define CAP_ 50.0f
#define EPS_ 1e-6f
#define CROSS_OK (-7)
#define KINV (-2147483647 - 1)

typedef __bf16 bf8_t __attribute__((ext_vector_type(8)));
typedef float fx4 __attribute__((ext_vector_type(4)));
#define MFMA16(a, b, c) __builtin_amdgcn_mfma_f32_16x16x32_bf16((a), (b), (c), 0, 0, 0)

typedef __attribute__((address_space(1))) unsigned int gas_u32;
typedef __attribute__((address_space(3))) unsigned int las_u32;
__device__ __forceinline__ void gl2lds16(const void* g, void* l) {
    __builtin_amdgcn_global_load_lds((const gas_u32*)g, (las_u32*)l, 16, 0, 0);
}

union U4 { __bf16 b[4]; unsigned long long u; };

// p = exp(50*tanh(dot*SCALE/50) - 50) = exp(-100/(exp(dot*2*SCALE/50)+1))
__device__ __forceinline__ float pexp(float dot) {
    float e = __expf(dot * (2.0f * SCALE_ / CAP_));
    return __expf(-(2.0f * CAP_) / (e + 1.0f));
}

// ---------------- fp32 -> bf16 (hi only) ----------------
__global__ __launch_bounds__(256) void tobf16(const float* __restrict__ x,
                                              __bf16* __restrict__ y, int n4) {
    int i = blockIdx.x * 256 + threadIdx.x;
    if (i >= n4) return;
    float4 v = ((const float4*)x)[i];
    U4 p;
    p.b[0] = (__bf16)v.x; p.b[1] = (__bf16)v.y;
    p.b[2] = (__bf16)v.z; p.b[3] = (__bf16)v.w;
    *(unsigned long long*)&y[(size_t)i * 4] = p.u;
}

// ---------------- transpose + split: W (KxN fp32) -> WT hi/lo (NxK bf16) -----
__global__ __launch_bounds__(256) void tsplit(const float* __restrict__ W,
                                              __bf16* __restrict__ Th,
                                              __bf16* __restrict__ Tl, int K, int N) {
    __shared__ float tile[32][33];
    const int t = threadIdx.x, tx = t & 31, ty = t >> 5;
    const int k0 = blockIdx.x * 32, n0 = blockIdx.y * 32;
#pragma unroll
    for (int r = 0; r < 4; ++r)
        tile[ty + r * 8][tx] = W[(size_t)(k0 + ty + r * 8) * N + n0 + tx];
    __syncthreads();
#pragma unroll
    for (int r = 0; r < 4; ++r) {
        float v = tile[tx][ty + r * 8];
        __bf16 h = (__bf16)v;
        size_t o = (size_t)(n0 + ty + r * 8) * K + k0 + tx;
        Th[o] = h;
        Tl[o] = (__bf16)(v - (float)h);
    }
}

// ---------------- shared GEMM core: 128x128 tile, BK=32, gl2lds staging ------
template <int NPASS>
__device__ __forceinline__ void gemm_core(
    const __bf16* __restrict__ Ah, const __bf16* __restrict__ Al,
    const __bf16* __restrict__ Bh, const __bf16* __restrict__ Bl,
    int row0, int col0, int K,
    __bf16* As0, __bf16* As1, __bf16* Bs0, __bf16* Bs1, fx4 (&acc)[4][4]) {
    const int tid = threadIdx.x, lane = tid & 63, wv = tid >> 6;
    const int l15 = lane & 15, lq = lane >> 4;
    const int wm = (wv >> 1) * 64, wn = (wv & 1) * 64;
    for (int k0 = 0; k0 < K; k0 += 32) {
        __syncthreads();
#pragma unroll
        for (int s = 0; s < 2; ++s) {
            int ch = (wv * 2 + s) * 64 + lane;       // 0..511
            int r = ch >> 2, kc = ch & 3;
            size_t ga = (size_t)(row0 + r) * K + k0 + kc * 8;
            size_t gb = (size_t)(col0 + r) * K + k0 + kc * 8;
            gl2lds16(Ah + ga, As0 + ch * 8);
            if (NPASS == 3) gl2lds16(Al + ga, As1 + ch * 8);
            gl2lds16(Bh + gb, Bs0 + ch * 8);
            gl2lds16(Bl + gb, Bs1 + ch * 8);
        }
        __syncthreads();
        bf8_t ah[4], al[4], bh[4], bl[4];
#pragma unroll
        for (int i = 0; i < 4; ++i) {
            int off = (wm + i * 16 + l15) * 32 + lq * 8;
            ah[i] = *(const bf8_t*)(As0 + off);
            if (NPASS == 3) al[i] = *(const bf8_t*)(As1 + off);
        }
#pragma unroll
        for (int j = 0; j < 4; ++j) {
            int off = (wn + j * 16 + l15) * 32 + lq * 8;
            bh[j] = *(const bf8_t*)(Bs0 + off);
            bl[j] = *(const bf8_t*)(Bs1 + off);
        }
#pragma unroll
        for (int i = 0; i < 4; ++i)
#pragma unroll
            for (int j = 0; j < 4; ++j) {
                acc[i][j] = MFMA16(ah[i], bh[j], acc[i][j]);
                acc[i][j] = MFMA16(ah[i], bl[j], acc[i][j]);
                if (NPASS == 3) acc[i][j] = MFMA16(al[i], bh[j], acc[i][j]);
            }
    }
}

// ---------------- fused projection GEMM (hs->q,k,v ; enc->kc,vc) ------------
__global__ __launch_bounds__(256) void gemm_proj(
    const __bf16* __restrict__ hsb, const __bf16* __restrict__ encb,
    const __bf16* __restrict__ BTh, const __bf16* __restrict__ BTl,
    float* __restrict__ qf32, float* __restrict__ ksf, float* __restrict__ kcf,
    __bf16* __restrict__ vtS, __bf16* __restrict__ vtC) {
    __shared__ __bf16 As0[4096], Bs0[4096], Bs1[4096];
    const int bx = blockIdx.x, row0 = blockIdx.y * 128;
    const __bf16* A;
    float* Ck; __bf16* Cv; int col0;
    if (bx < 32) { A = hsb;  col0 = bx * 128;               Ck = ksf; Cv = vtS; }
    else         { A = encb; col0 = (bx - 32) * 128 + 2048; Ck = kcf; Cv = vtC; }
    fx4 acc[4][4];
#pragma unroll
    for (int i = 0; i < 4; ++i)
#pragma unroll
        for (int j = 0; j < 4; ++j) acc[i][j] = (fx4){0.f, 0.f, 0.f, 0.f};
    gemm_core<2>(A, nullptr, BTh, BTl, row0, col0, D_, As0, nullptr, Bs0, Bs1, acc);

    const int tid = threadIdx.x, lane = tid & 63, wv = tid >> 6;
    const int l15 = lane & 15, lq = lane >> 4;
    const int wm = (wv >> 1) * 64, wn = (wv & 1) * 64;
    const int mode = (col0 < 2048) ? 0 : (col0 < 3072 ? 1 : 2);
#pragma unroll
    for (int i = 0; i < 4; ++i)
#pragma unroll
        for (int j = 0; j < 4; ++j) {
            int mb = row0 + wm + i * 16 + lq * 4;
            int n = col0 + wn + j * 16 + l15;
            if (mode == 0) {
#pragma unroll
                for (int r = 0; r < 4; ++r)
                    qf32[(size_t)(mb + r) * 2048 + n] = acc[i][j][r];
            } else if (mode == 1) {
                int nk = n - 2048;
#pragma unroll
                for (int r = 0; r < 4; ++r)
                    Ck[(size_t)(mb + r) * 1024 + nk] = acc[i][j][r];
            } else {
                int nv = n - 3072;
                int b = mb >> 10, s = mb & 1023;
                int kv = nv >> 8, d = nv & 255;
                U4 pk;
#pragma unroll
                for (int r = 0; r < 4; ++r) pk.b[r] = (__bf16)acc[i][j][r];
                *(unsigned long long*)&Cv[((size_t)(b * KV_ + kv) * HD_ + d) * 1024 + s] = pk.u;
            }
        }
}

// ---------------- output GEMM (3-term split) ----------------
__global__ __launch_bounds__(256) void gemm_out(
    const __bf16* __restrict__ Ah, const __bf16* __restrict__ Al,
    const __bf16* __restrict__ Bh, const __bf16* __restrict__ Bl,
    float* __restrict__ C) {
    __shared__ __bf16 As0[4096], As1[4096], Bs0[4096], Bs1[4096];
    const int row0 = blockIdx.y * 128, col0 = blockIdx.x * 128;
    fx4 acc[4][4];
#pragma unroll
    for (int i = 0; i < 4; ++i)
#pragma unroll
        for (int j = 0; j < 4; ++j) acc[i][j] = (fx4){0.f, 0.f, 0.f, 0.f};
    gemm_core<3>(Ah, Al, Bh, Bl, row0, col0, 2048, As0, As1, Bs0, Bs1, acc);
    const int tid = threadIdx.x, lane = tid & 63, wv = tid >> 6;
    const int l15 = lane & 15, lq = lane >> 4;
    const int wm = (wv >> 1) * 64, wn = (wv & 1) * 64;
#pragma unroll
    for (int i = 0; i < 4; ++i)
#pragma unroll
        for (int j = 0; j < 4; ++j) {
            int mb = row0 + wm + i * 16 + lq * 4;
            int n = col0 + wn + j * 16 + l15;
#pragma unroll
            for (int r = 0; r < 4; ++r)
                C[(size_t)(mb + r) * 2048 + n] = acc[i][j][r];
        }
}

// ---------------- RMSNorm (+optional RoPE): fp32 in, bf16 out ---------------
__global__ __launch_bounds__(256) void rmsnorm_rope(const float* __restrict__ x,
                                                    __bf16* __restrict__ out,
                                                    const float* __restrict__ w,
                                                    const float* __restrict__ cs,
                                                    const float* __restrict__ sn,
                                                    int nheads, int do_rope, int trans) {
    const int tid = threadIdx.x;
    const size_t base = (size_t)blockIdx.x * HD_;
    float v = x[base + tid];
    float ss = v * v;
#pragma unroll
    for (int off = 32; off; off >>= 1) ss += __shfl_down(ss, off);
    __shared__ float red[4];
    __shared__ float ybuf[HD_];
    const int lane = tid & 63, wvi = tid >> 6;
    if (lane == 0) red[wvi] = ss;
    __syncthreads();
    float tot = red[0] + red[1] + red[2] + red[3];
    float scale = rsqrtf(tot * (1.0f / HD_) + EPS_);
    float y = v * scale * (1.0f + w[tid]);
    const int m = blockIdx.x / nheads;
    if (do_rope) {
        ybuf[tid] = y;
        __syncthreads();
        float rot = (tid < HD_ / 2) ? -ybuf[tid + HD_ / 2] : ybuf[tid - HD_ / 2];
        size_t coff = (size_t)m * HD_;
        y = y * cs[coff + tid] + rot * sn[coff + tid];
    }
    size_t oidx;
    if (trans) {
        int hh = blockIdx.x % nheads;
        int b = m >> 10, s = m & 1023;
        oidx = ((size_t)(b * nheads + hh) * 1024 + s) * HD_ + tid;
    } else {
        oidx = base + tid;
    }
    out[oidx] = (__bf16)y;
}

// ---------------- segment scan + key info ----------------
__global__ void segscan(const int* __restrict__ pos, const int* __restrict__ dm,
                        const int* __restrict__ em, int* __restrict__ seg,
                        int* __restrict__ ki) {
    const int b = blockIdx.x, s = threadIdx.x;
    __shared__ int sh[1024];
    int p = pos[b * S_ + s];
    int r = (s == 0) ? 1 : (p <= pos[b * S_ + s - 1] ? 1 : 0);
    sh[s] = r;
    __syncthreads();
    for (int off = 1; off < 1024; off <<= 1) {
        int v = sh[s];
        int u = (s >= off) ? sh[s - off] : 0;
        __syncthreads();
        sh[s] = v + u;
        __syncthreads();
    }
    int sv = sh[s];
    seg[b * S_ + s] = sv;
    ki[b * 2048 + s] = dm[b * S_ + s] ? sv : KINV;
    ki[b * 2048 + 1024 + s] = em[b * E_ + s] ? CROSS_OK : KINV;
}

// ---------------- attention partial: 1 wave / block, no barriers ------------
// blockIdx: bit0 = cross-half, then qt(64) | h(8) | b(2). 16 q-rows per wave.
// waves_per_eu(2,2): allow ~256 VGPRs so all 32 K/V tile loads stay in flight
// (at the default occupancy target the compiler allocated 68 VGPRs and
// serialized the loads -> latency-bound, MfmaUtil 3.4%).
__global__ __attribute__((amdgpu_waves_per_eu(2, 2))) __launch_bounds__(64) void attn_part(
    const __bf16* __restrict__ qb,   // [B][S][H][256]
    const __bf16* __restrict__ kb,   // [B][KV][S][256]
    const __bf16* __restrict__ kcb,  // [B][KV][E][256]
    const __bf16* __restrict__ vtS,  // [B][KV][256][S]
    const __bf16* __restrict__ vtC,  // [B][KV][256][E]
    const int* __restrict__ seg, const int* __restrict__ ki,
    float* __restrict__ oS, float* __restrict__ oC,
    float* __restrict__ lS, float* __restrict__ lC) {
    const int lane = threadIdx.x, l15 = lane & 15, lq = lane >> 4;
    int idx = blockIdx.x;
    const int cross = idx & 1; idx >>= 1;
    const int qt = idx & 63, h = (idx >> 6) & 7, b = idx >> 9;
    const int s0 = qt * 16, kv = h >> 1;
    __shared__ __bf16 Ps[16 * 40];               // padded stride 40

    bf8_t qf[8];
    const __bf16* qrow = qb + ((size_t)(b * S_ + s0 + l15) * H_ + h) * HD_;
#pragma unroll
    for (int f = 0; f < 8; ++f) qf[f] = *(const bf8_t*)(qrow + f * 32 + lq * 8);
    const int qpos = s0 + l15;
    const int segq = seg[b * S_ + qpos];
    const int tgt = cross ? CROSS_OK : segq;

    fx4 accO[16];
#pragma unroll
    for (int j = 0; j < 16; ++j) accO[j] = (fx4){0.f, 0.f, 0.f, 0.f};
    float lsum = 0.f;

    int kt_lo, kt_hi;
    const __bf16 *Kb, *Vb;
    const int* kio;
    if (!cross) {
        int lo = s0 - 511; if (lo < 0) lo = 0;
        kt_lo = lo & ~31; kt_hi = s0 + 15;
        Kb = kb + (size_t)(b * KV_ + kv) * 1024 * 256;
        Vb = vtS + (size_t)(b * KV_ + kv) * 256 * 1024;
        kio = ki + b * 2048;
    } else {
        kt_lo = 0; kt_hi = 1023;
        Kb = kcb + (size_t)(b * KV_ + kv) * 1024 * 256;
        Vb = vtC + (size_t)(b * KV_ + kv) * 256 * 1024;
        kio = ki + b * 2048 + 1024;
    }

    for (int kt0 = kt_lo; kt0 <= kt_hi; kt0 += 32) {
        // ---- issue ALL 32 tile loads (K: 16, V: 16) before any use ----
        const __bf16* kp0 = Kb + (size_t)(kt0 + l15) * 256 + lq * 8;
        const __bf16* kp1 = kp0 + 16 * 256;
        const __bf16* vp  = Vb + (size_t)l15 * 1024 + kt0 + lq * 8;
        bf8_t kf[16], vf[16];
#pragma unroll
        for (int f = 0; f < 8; ++f) kf[f] = *(const bf8_t*)(kp0 + f * 32);
#pragma unroll
        for (int f = 0; f < 8; ++f) kf[8 + f] = *(const bf8_t*)(kp1 + f * 32);
#pragma unroll
        for (int j = 0; j < 16; ++j) vf[j] = *(const bf8_t*)(vp + (size_t)j * 16384);
        int4 ki0 = *(const int4*)(kio + kt0 + lq * 4);
        int4 ki1 = *(const int4*)(kio + kt0 + 16 + lq * 4);

        fx4 sc0 = (fx4){0.f, 0.f, 0.f, 0.f}, sc1 = (fx4){0.f, 0.f, 0.f, 0.f};
#pragma unroll
        for (int f = 0; f < 8; ++f) sc0 = MFMA16(kf[f], qf[f], sc0);
#pragma unroll
        for (int f = 0; f < 8; ++f) sc1 = MFMA16(kf[8 + f], qf[f], sc1);

        int ka0[4] = {ki0.x, ki0.y, ki0.z, ki0.w};
        int ka1[4] = {ki1.x, ki1.y, ki1.z, ki1.w};
        U4 p0, p1;
#pragma unroll
        for (int r = 0; r < 4; ++r) {
            int key0 = kt0 + lq * 4 + r;
            float e0 = pexp(sc0[r]);
            float e1 = pexp(sc1[r]);
            bool ok0 = (ka0[r] == tgt) && (cross || (unsigned)(qpos - key0) < WINDOW_);
            bool ok1 = (ka1[r] == tgt) && (cross || (unsigned)(qpos - key0 - 16) < WINDOW_);
            float v0 = ok0 ? e0 : 0.f;
            float v1 = ok1 ? e1 : 0.f;
            lsum += v0 + v1;
            p0.b[r] = (__bf16)v0;
            p1.b[r] = (__bf16)v1;
        }
        *(unsigned long long*)&Ps[l15 * 40 + lq * 4] = p0.u;
        *(unsigned long long*)&Ps[l15 * 40 + 16 + lq * 4] = p1.u;
        bf8_t pf = *(const bf8_t*)&Ps[l15 * 40 + lq * 8];
#pragma unroll
        for (int j = 0; j < 16; ++j) accO[j] = MFMA16(pf, vf[j], accO[j]);
    }
    lsum += __shfl_xor(lsum, 16);
    lsum += __shfl_xor(lsum, 32);
    float* oP = cross ? oC : oS;
    float* lP = cross ? lC : lS;
#pragma unroll
    for (int j = 0; j < 16; ++j)
#pragma unroll
        for (int r = 0; r < 4; ++r)
            oP[(size_t)(b * S_ + s0 + lq * 4 + r) * 2048 + h * 256 + j * 16 + l15] = accO[j][r];
    if (lane < 16) lP[(size_t)(b * H_ + h) * 1024 + s0 + l15] = lsum;
}

// ---------------- merge self+cross partials, normalize, split-bf16 ----------
__global__ __launch_bounds__(256) void merge_attn(
    const float* __restrict__ oS, const float* __restrict__ oC,
    const float* __restrict__ lS, const float* __restrict__ lC,
    __bf16* __restrict__ aH, __bf16* __restrict__ aL) {
    int i = blockIdx.x * 256 + threadIdx.x;       // float4 idx over [2048][512]
    float4 a = ((const float4*)oS)[i];
    float4 c = ((const float4*)oC)[i];
    int m = i >> 9;
    int h = (i >> 6) & 7;
    int b = m >> 10, s = m & 1023;
    size_t li = (size_t)(b * H_ + h) * 1024 + s;
    float inv = 1.0f / (lS[li] + lC[li]);
    float o[4] = {(a.x + c.x) * inv, (a.y + c.y) * inv, (a.z + c.z) * inv, (a.w + c.w) * inv};
    U4 ph, pl;
#pragma unroll
    for (int r = 0; r < 4; ++r) {
        __bf16 hi = (__bf16)o[r];
        ph.b[r] = hi;
        pl.b[r] = (__bf16)(o[r] - (float)hi);
    }
    *(unsigned long long*)&aH[(size_t)i * 4] = ph.u;
    *(unsigned long long*)&aL[(size_t)i * 4] = pl.u;
}

extern "C" void kernel_launch(void* const* d_in, const int* in_sizes, int n_in,
                              void* d_out, int out_size, void* d_ws, size_t ws_size,
                              hipStream_t stream) {
    (void)in_sizes; (void)n_in; (void)out_size; (void)ws_size;
    const float* hs  = (const float*)d_in[0];
    const float* enc = (const float*)d_in[1];
    const float* cs  = (const float*)d_in[2];
    const float* sn  = (const float*)d_in[3];
    const float* wq  = (const float*)d_in[4];
    const float* wk  = (const float*)d_in[5];
    const float* wv  = (const float*)d_in[6];
    const float* wo  = (const float*)d_in[7];
    const float* qnw = (const float*)d_in[8];
    const float* knw = (const float*)d_in[9];
    const int* dm    = (const int*)d_in[10];
    const int* em    = (const int*)d_in[11];
    const int* pos   = (const int*)d_in[12];
    float* out = (float*)d_out;

    char* ws = (char*)d_ws;
    const size_t MB = 1ull << 20;
    __bf16* hs_bf   = (__bf16*)(ws + 0 * MB);    // 8 MB   (dead after gemm_proj)
    __bf16* enc_bf  = (__bf16*)(ws + 8 * MB);    // 8 MB   (dead after gemm_proj)
    __bf16* wqkvTH  = (__bf16*)(ws + 16 * MB);   // 16 MB  (dead after gemm_proj)
    __bf16* wqkvTL  = (__bf16*)(ws + 32 * MB);   // 16 MB
    __bf16* woTH    = (__bf16*)(ws + 48 * MB);   // 8 MB
    __bf16* woTL    = (__bf16*)(ws + 56 * MB);   // 8 MB
    float*  qf32    = (float*)(ws + 64 * MB);    // 16 MB  (dead after rmsnorm q)
    float*  ksf     = (float*)(ws + 80 * MB);    // 8 MB   (dead after rmsnorm k)
    float*  kcf     = (float*)(ws + 88 * MB);    // 8 MB   (dead after rmsnorm kc)
    __bf16* k_bf    = (__bf16*)(ws + 104 * MB);  // 4 MB   [B][KV][S][256]
    __bf16* kc_bf   = (__bf16*)(ws + 108 * MB);  // 4 MB
    __bf16* vtS     = (__bf16*)(ws + 112 * MB);  // 4 MB   [B][KV][256][S]
    __bf16* vtC     = (__bf16*)(ws + 116 * MB);  // 4 MB
    int*    seg     = (int*)(ws + 120 * MB);     // 8 KB
    int*    kinfo   = (int*)(ws + 121 * MB);     // 16 KB
    float*  lS      = (float*)(ws + 122 * MB);   // 64 KB
    float*  lC      = (float*)(ws + 123 * MB);   // 64 KB
    __bf16* q_bf    = (__bf16*)(ws + 124 * MB);  // 8 MB   [B][S][H][256]
    // reuse of dead regions:
    float*  oS      = (float*)(ws + 64 * MB);    // 16.78 MB over qf32/ksf
    float*  oC      = (float*)(ws + 81 * MB);    // 16.78 MB over kcf tail
    __bf16* aoutH   = (__bf16*)(ws + 0 * MB);    // 8.39 MB over hs_bf
    __bf16* aoutL   = (__bf16*)(ws + 9 * MB);    // 8.39 MB over enc_bf/wqkvTH

    const int M = B_ * S_;   // 2048

    tobf16<<<4096, 256, 0, stream>>>(hs, hs_bf, M * D_ / 4);
    tobf16<<<4096, 256, 0, stream>>>(enc, enc_bf, M * D_ / 4);
    tsplit<<<dim3(64, 64), 256, 0, stream>>>(wq, wqkvTH, wqkvTL, D_, 2048);
    tsplit<<<dim3(64, 32), 256, 0, stream>>>(wk, wqkvTH + (size_t)2048 * 2048,
                                             wqkvTL + (size_t)2048 * 2048, D_, 1024);
    tsplit<<<dim3(64, 32), 256, 0, stream>>>(wv, wqkvTH + (size_t)3072 * 2048,
                                             wqkvTL + (size_t)3072 * 2048, D_, 1024);
    tsplit<<<dim3(64, 64), 256, 0, stream>>>(wo, woTH, woTL, 2048, D_);

    gemm_proj<<<dim3(48, 16), 256, 0, stream>>>(hs_bf, enc_bf, wqkvTH, wqkvTL,
                                                qf32, ksf, kcf, vtS, vtC);

    rmsnorm_rope<<<16384, 256, 0, stream>>>(qf32, q_bf, qnw, cs, sn, H_, 1, 0);
    rmsnorm_rope<<<8192, 256, 0, stream>>>(ksf, k_bf, knw, cs, sn, KV_, 1, 1);
    rmsnorm_rope<<<8192, 256, 0, stream>>>(kcf, kc_bf, knw, cs, sn, KV_, 0, 1);
    segscan<<<B_, 1024, 0, stream>>>(pos, dm, em, seg, kinfo);

    attn_part<<<2048, 64, 0, stream>>>(q_bf, k_bf, kc_bf, vtS, vtC, seg, kinfo,
                                       oS, oC, lS, lC);
    merge_attn<<<4096, 256, 0, stream>>>(oS, oC, lS, lC, aoutH, aoutL);

    gemm_out<<<dim3(16, 16), 256, 0, stream>>>(aoutH, aoutL, woTH, woTL, out);
}

// Round 5
// 624.506 us; speedup vs baseline: 3.8730x; 1.0324x over previous
//
#include <hip/hip_runtime.h>
#include <math.h>

#define B_ 2
#define S_ 1024
#define E_ 1024
#define D_ 2048
#define H_ 8
#define KV_ 4
#define HD_ 256
#define WINDOW_ 512u
#define SCALE_ 0.0625f
#define CAP_ 50.0f
#define EPS_ 1e-6f
#define CROSS_OK (-7)
#define KINV (-2147483647 - 1)

typedef __bf16 bf8_t __attribute__((ext_vector_type(8)));
typedef float fx4 __attribute__((ext_vector_type(4)));
#define MFMA16(a, b, c) __builtin_amdgcn_mfma_f32_16x16x32_bf16((a), (b), (c), 0, 0, 0)

typedef __attribute__((address_space(1))) unsigned int gas_u32;
typedef __attribute__((address_space(3))) unsigned int las_u32;
__device__ __forceinline__ void gl2lds16(const void* g, void* l) {
    __builtin_amdgcn_global_load_lds((const gas_u32*)g, (las_u32*)l, 16, 0, 0);
}

union U4 { __bf16 b[4]; unsigned long long u; };

// p = exp(50*tanh(dot*SCALE/50) - 50) = exp(-100/(exp(dot*2*SCALE/50)+1))
__device__ __forceinline__ float pexp(float dot) {
    float e = __expf(dot * (2.0f * SCALE_ / CAP_));
    return __expf(-(2.0f * CAP_) / (e + 1.0f));
}

// ---------------- fp32 -> bf16 (hi only) ----------------
__global__ __launch_bounds__(256) void tobf16(const float* __restrict__ x,
                                              __bf16* __restrict__ y, int n4) {
    int i = blockIdx.x * 256 + threadIdx.x;
    if (i >= n4) return;
    float4 v = ((const float4*)x)[i];
    U4 p;
    p.b[0] = (__bf16)v.x; p.b[1] = (__bf16)v.y;
    p.b[2] = (__bf16)v.z; p.b[3] = (__bf16)v.w;
    *(unsigned long long*)&y[(size_t)i * 4] = p.u;
}

// ---------------- transpose + split: W (KxN fp32) -> WT hi/lo (NxK bf16) -----
__global__ __launch_bounds__(256) void tsplit(const float* __restrict__ W,
                                              __bf16* __restrict__ Th,
                                              __bf16* __restrict__ Tl, int K, int N) {
    __shared__ float tile[32][33];
    const int t = threadIdx.x, tx = t & 31, ty = t >> 5;
    const int k0 = blockIdx.x * 32, n0 = blockIdx.y * 32;
#pragma unroll
    for (int r = 0; r < 4; ++r)
        tile[ty + r * 8][tx] = W[(size_t)(k0 + ty + r * 8) * N + n0 + tx];
    __syncthreads();
#pragma unroll
    for (int r = 0; r < 4; ++r) {
        float v = tile[tx][ty + r * 8];
        __bf16 h = (__bf16)v;
        size_t o = (size_t)(n0 + ty + r * 8) * K + k0 + tx;
        Th[o] = h;
        Tl[o] = (__bf16)(v - (float)h);
    }
}

// ---------------- shared GEMM core: 128x128 tile, BK=32, gl2lds staging ------
template <int NPASS>
__device__ __forceinline__ void gemm_core(
    const __bf16* __restrict__ Ah, const __bf16* __restrict__ Al,
    const __bf16* __restrict__ Bh, const __bf16* __restrict__ Bl,
    int row0, int col0, int K,
    __bf16* As0, __bf16* As1, __bf16* Bs0, __bf16* Bs1, fx4 (&acc)[4][4]) {
    const int tid = threadIdx.x, lane = tid & 63, wv = tid >> 6;
    const int l15 = lane & 15, lq = lane >> 4;
    const int wm = (wv >> 1) * 64, wn = (wv & 1) * 64;
    for (int k0 = 0; k0 < K; k0 += 32) {
        __syncthreads();
#pragma unroll
        for (int s = 0; s < 2; ++s) {
            int ch = (wv * 2 + s) * 64 + lane;       // 0..511
            int r = ch >> 2, kc = ch & 3;
            size_t ga = (size_t)(row0 + r) * K + k0 + kc * 8;
            size_t gb = (size_t)(col0 + r) * K + k0 + kc * 8;
            gl2lds16(Ah + ga, As0 + ch * 8);
            if (NPASS == 3) gl2lds16(Al + ga, As1 + ch * 8);
            gl2lds16(Bh + gb, Bs0 + ch * 8);
            gl2lds16(Bl + gb, Bs1 + ch * 8);
        }
        __syncthreads();
        bf8_t ah[4], al[4], bh[4], bl[4];
#pragma unroll
        for (int i = 0; i < 4; ++i) {
            int off = (wm + i * 16 + l15) * 32 + lq * 8;
            ah[i] = *(const bf8_t*)(As0 + off);
            if (NPASS == 3) al[i] = *(const bf8_t*)(As1 + off);
        }
#pragma unroll
        for (int j = 0; j < 4; ++j) {
            int off = (wn + j * 16 + l15) * 32 + lq * 8;
            bh[j] = *(const bf8_t*)(Bs0 + off);
            bl[j] = *(const bf8_t*)(Bs1 + off);
        }
#pragma unroll
        for (int i = 0; i < 4; ++i)
#pragma unroll
            for (int j = 0; j < 4; ++j) {
                acc[i][j] = MFMA16(ah[i], bh[j], acc[i][j]);
                acc[i][j] = MFMA16(ah[i], bl[j], acc[i][j]);
                if (NPASS == 3) acc[i][j] = MFMA16(al[i], bh[j], acc[i][j]);
            }
    }
}

// ---------------- fused projection GEMM (hs->q,k,v ; enc->kc,vc) ------------
__global__ __launch_bounds__(256) void gemm_proj(
    const __bf16* __restrict__ hsb, const __bf16* __restrict__ encb,
    const __bf16* __restrict__ BTh, const __bf16* __restrict__ BTl,
    float* __restrict__ qf32, float* __restrict__ ksf, float* __restrict__ kcf,
    __bf16* __restrict__ vtS, __bf16* __restrict__ vtC) {
    __shared__ __bf16 As0[4096], Bs0[4096], Bs1[4096];
    const int bx = blockIdx.x, row0 = blockIdx.y * 128;
    const __bf16* A;
    float* Ck; __bf16* Cv; int col0;
    if (bx < 32) { A = hsb;  col0 = bx * 128;               Ck = ksf; Cv = vtS; }
    else         { A = encb; col0 = (bx - 32) * 128 + 2048; Ck = kcf; Cv = vtC; }
    fx4 acc[4][4];
#pragma unroll
    for (int i = 0; i < 4; ++i)
#pragma unroll
        for (int j = 0; j < 4; ++j) acc[i][j] = (fx4){0.f, 0.f, 0.f, 0.f};
    gemm_core<2>(A, nullptr, BTh, BTl, row0, col0, D_, As0, nullptr, Bs0, Bs1, acc);

    const int tid = threadIdx.x, lane = tid & 63, wv = tid >> 6;
    const int l15 = lane & 15, lq = lane >> 4;
    const int wm = (wv >> 1) * 64, wn = (wv & 1) * 64;
    const int mode = (col0 < 2048) ? 0 : (col0 < 3072 ? 1 : 2);
#pragma unroll
    for (int i = 0; i < 4; ++i)
#pragma unroll
        for (int j = 0; j < 4; ++j) {
            int mb = row0 + wm + i * 16 + lq * 4;
            int n = col0 + wn + j * 16 + l15;
            if (mode == 0) {
#pragma unroll
                for (int r = 0; r < 4; ++r)
                    qf32[(size_t)(mb + r) * 2048 + n] = acc[i][j][r];
            } else if (mode == 1) {
                int nk = n - 2048;
#pragma unroll
                for (int r = 0; r < 4; ++r)
                    Ck[(size_t)(mb + r) * 1024 + nk] = acc[i][j][r];
            } else {
                int nv = n - 3072;
                int b = mb >> 10, s = mb & 1023;
                int kv = nv >> 8, d = nv & 255;
                U4 pk;
#pragma unroll
                for (int r = 0; r < 4; ++r) pk.b[r] = (__bf16)acc[i][j][r];
                *(unsigned long long*)&Cv[((size_t)(b * KV_ + kv) * HD_ + d) * 1024 + s] = pk.u;
            }
        }
}

// ---------------- output GEMM (3-term split) ----------------
__global__ __launch_bounds__(256) void gemm_out(
    const __bf16* __restrict__ Ah, const __bf16* __restrict__ Al,
    const __bf16* __restrict__ Bh, const __bf16* __restrict__ Bl,
    float* __restrict__ C) {
    __shared__ __bf16 As0[4096], As1[4096], Bs0[4096], Bs1[4096];
    const int row0 = blockIdx.y * 128, col0 = blockIdx.x * 128;
    fx4 acc[4][4];
#pragma unroll
    for (int i = 0; i < 4; ++i)
#pragma unroll
        for (int j = 0; j < 4; ++j) acc[i][j] = (fx4){0.f, 0.f, 0.f, 0.f};
    gemm_core<3>(Ah, Al, Bh, Bl, row0, col0, 2048, As0, As1, Bs0, Bs1, acc);
    const int tid = threadIdx.x, lane = tid & 63, wv = tid >> 6;
    const int l15 = lane & 15, lq = lane >> 4;
    const int wm = (wv >> 1) * 64, wn = (wv & 1) * 64;
#pragma unroll
    for (int i = 0; i < 4; ++i)
#pragma unroll
        for (int j = 0; j < 4; ++j) {
            int mb = row0 + wm + i * 16 + lq * 4;
            int n = col0 + wn + j * 16 + l15;
#pragma unroll
            for (int r = 0; r < 4; ++r)
                C[(size_t)(mb + r) * 2048 + n] = acc[i][j][r];
        }
}

// ---------------- RMSNorm (+optional RoPE): fp32 in, bf16 out ---------------
__global__ __launch_bounds__(256) void rmsnorm_rope(const float* __restrict__ x,
                                                    __bf16* __restrict__ out,
                                                    const float* __restrict__ w,
                                                    const float* __restrict__ cs,
                                                    const float* __restrict__ sn,
                                                    int nheads, int do_rope, int trans) {
    const int tid = threadIdx.x;
    const size_t base = (size_t)blockIdx.x * HD_;
    float v = x[base + tid];
    float ss = v * v;
#pragma unroll
    for (int off = 32; off; off >>= 1) ss += __shfl_down(ss, off);
    __shared__ float red[4];
    __shared__ float ybuf[HD_];
    const int lane = tid & 63, wvi = tid >> 6;
    if (lane == 0) red[wvi] = ss;
    __syncthreads();
    float tot = red[0] + red[1] + red[2] + red[3];
    float scale = rsqrtf(tot * (1.0f / HD_) + EPS_);
    float y = v * scale * (1.0f + w[tid]);
    const int m = blockIdx.x / nheads;
    if (do_rope) {
        ybuf[tid] = y;
        __syncthreads();
        float rot = (tid < HD_ / 2) ? -ybuf[tid + HD_ / 2] : ybuf[tid - HD_ / 2];
        size_t coff = (size_t)m * HD_;
        y = y * cs[coff + tid] + rot * sn[coff + tid];
    }
    size_t oidx;
    if (trans) {
        int hh = blockIdx.x % nheads;
        int b = m >> 10, s = m & 1023;
        oidx = ((size_t)(b * nheads + hh) * 1024 + s) * HD_ + tid;
    } else {
        oidx = base + tid;
    }
    out[oidx] = (__bf16)y;
}

// ---------------- segment scan + key info ----------------
__global__ void segscan(const int* __restrict__ pos, const int* __restrict__ dm,
                        const int* __restrict__ em, int* __restrict__ seg,
                        int* __restrict__ ki) {
    const int b = blockIdx.x, s = threadIdx.x;
    __shared__ int sh[1024];
    int p = pos[b * S_ + s];
    int r = (s == 0) ? 1 : (p <= pos[b * S_ + s - 1] ? 1 : 0);
    sh[s] = r;
    __syncthreads();
    for (int off = 1; off < 1024; off <<= 1) {
        int v = sh[s];
        int u = (s >= off) ? sh[s - off] : 0;
        __syncthreads();
        sh[s] = v + u;
        __syncthreads();
    }
    int sv = sh[s];
    seg[b * S_ + s] = sv;
    ki[b * 2048 + s] = dm[b * S_ + s] ? sv : KINV;
    ki[b * 2048 + 1024 + s] = em[b * E_ + s] ? CROSS_OK : KINV;
}

// ---------------- attention partial: 1 wave / block, no barriers ------------
// 3-way key-chunk split per (b,h,qtile): ck0=self-window, ck1=cross[0,512),
// ck2=cross[512,1024). sched_barrier(0) pins all 32 tile loads before compute
// (R4: allocator sank loads into ~8 serialized latency exposures/tile).
__global__ __attribute__((amdgpu_waves_per_eu(1, 2))) __launch_bounds__(64) void attn_part(
    const __bf16* __restrict__ qb,   // [B][S][H][256]
    const __bf16* __restrict__ kb,   // [B][KV][S][256]
    const __bf16* __restrict__ kcb,  // [B][KV][E][256]
    const __bf16* __restrict__ vtS,  // [B][KV][256][S]
    const __bf16* __restrict__ vtC,  // [B][KV][256][E]
    const int* __restrict__ seg, const int* __restrict__ ki,
    float* __restrict__ o0, float* __restrict__ o1, float* __restrict__ o2,
    float* __restrict__ l0, float* __restrict__ l1, float* __restrict__ l2) {
    const int lane = threadIdx.x, l15 = lane & 15, lq = lane >> 4;
    int idx = blockIdx.x;
    const int ck = idx % 3; idx /= 3;
    const int qt = idx & 63, h = (idx >> 6) & 7, b = idx >> 9;
    const int s0 = qt * 16, kv = h >> 1;
    const int cross = (ck != 0);
    __shared__ __bf16 Ps[16 * 40];               // padded stride 40

    bf8_t qf[8];
    const __bf16* qrow = qb + ((size_t)(b * S_ + s0 + l15) * H_ + h) * HD_;
#pragma unroll
    for (int f = 0; f < 8; ++f) qf[f] = *(const bf8_t*)(qrow + f * 32 + lq * 8);
    const int qpos = s0 + l15;
    const int segq = seg[b * S_ + qpos];
    const int tgt = cross ? CROSS_OK : segq;

    fx4 accO[16];
#pragma unroll
    for (int j = 0; j < 16; ++j) accO[j] = (fx4){0.f, 0.f, 0.f, 0.f};
    float lsum = 0.f;

    int kt_lo, kt_hi;
    const __bf16 *Kb, *Vb;
    const int* kio;
    if (!cross) {
        int lo = s0 - 511; if (lo < 0) lo = 0;
        kt_lo = lo & ~31; kt_hi = s0 + 15;
        Kb = kb + (size_t)(b * KV_ + kv) * 1024 * 256;
        Vb = vtS + (size_t)(b * KV_ + kv) * 256 * 1024;
        kio = ki + b * 2048;
    } else {
        kt_lo = (ck == 1) ? 0 : 512;
        kt_hi = kt_lo + 511;
        Kb = kcb + (size_t)(b * KV_ + kv) * 1024 * 256;
        Vb = vtC + (size_t)(b * KV_ + kv) * 256 * 1024;
        kio = ki + b * 2048 + 1024;
    }

    for (int kt0 = kt_lo; kt0 <= kt_hi; kt0 += 32) {
        // ---- issue ALL 32 tile loads (K: 16, V: 16) before any use ----
        const __bf16* kp0 = Kb + (size_t)(kt0 + l15) * 256 + lq * 8;
        const __bf16* kp1 = kp0 + 16 * 256;
        const __bf16* vp  = Vb + (size_t)l15 * 1024 + kt0 + lq * 8;
        bf8_t kf[16], vf[16];
#pragma unroll
        for (int f = 0; f < 8; ++f) kf[f] = *(const bf8_t*)(kp0 + f * 32);
#pragma unroll
        for (int f = 0; f < 8; ++f) kf[8 + f] = *(const bf8_t*)(kp1 + f * 32);
#pragma unroll
        for (int j = 0; j < 16; ++j) vf[j] = *(const bf8_t*)(vp + (size_t)j * 16384);
        int4 ki0 = *(const int4*)(kio + kt0 + lq * 4);
        int4 ki1 = *(const int4*)(kio + kt0 + 16 + lq * 4);
        __builtin_amdgcn_sched_barrier(0);   // loads may not sink past this

        fx4 sc0 = (fx4){0.f, 0.f, 0.f, 0.f}, sc1 = (fx4){0.f, 0.f, 0.f, 0.f};
#pragma unroll
        for (int f = 0; f < 8; ++f) sc0 = MFMA16(kf[f], qf[f], sc0);
#pragma unroll
        for (int f = 0; f < 8; ++f) sc1 = MFMA16(kf[8 + f], qf[f], sc1);

        int ka0[4] = {ki0.x, ki0.y, ki0.z, ki0.w};
        int ka1[4] = {ki1.x, ki1.y, ki1.z, ki1.w};
        U4 p0, p1;
#pragma unroll
        for (int r = 0; r < 4; ++r) {
            int key0 = kt0 + lq * 4 + r;
            float e0 = pexp(sc0[r]);
            float e1 = pexp(sc1[r]);
            bool ok0 = (ka0[r] == tgt) && (cross || (unsigned)(qpos - key0) < WINDOW_);
            bool ok1 = (ka1[r] == tgt) && (cross || (unsigned)(qpos - key0 - 16) < WINDOW_);
            float v0 = ok0 ? e0 : 0.f;
            float v1 = ok1 ? e1 : 0.f;
            lsum += v0 + v1;
            p0.b[r] = (__bf16)v0;
            p1.b[r] = (__bf16)v1;
        }
        *(unsigned long long*)&Ps[l15 * 40 + lq * 4] = p0.u;
        *(unsigned long long*)&Ps[l15 * 40 + 16 + lq * 4] = p1.u;
        bf8_t pf = *(const bf8_t*)&Ps[l15 * 40 + lq * 8];
#pragma unroll
        for (int j = 0; j < 16; ++j) accO[j] = MFMA16(pf, vf[j], accO[j]);
    }
    lsum += __shfl_xor(lsum, 16);
    lsum += __shfl_xor(lsum, 32);
    float* oP = (ck == 0) ? o0 : (ck == 1) ? o1 : o2;
    float* lP = (ck == 0) ? l0 : (ck == 1) ? l1 : l2;
#pragma unroll
    for (int j = 0; j < 16; ++j)
#pragma unroll
        for (int r = 0; r < 4; ++r)
            oP[(size_t)(b * S_ + s0 + lq * 4 + r) * 2048 + h * 256 + j * 16 + l15] = accO[j][r];
    if (lane < 16) lP[(size_t)(b * H_ + h) * 1024 + s0 + l15] = lsum;
}

// ---------------- merge 3 partials, normalize, split-bf16 ----------
__global__ __launch_bounds__(256) void merge_attn(
    const float* __restrict__ o0, const float* __restrict__ o1,
    const float* __restrict__ o2,
    const float* __restrict__ l0, const float* __restrict__ l1,
    const float* __restrict__ l2,
    __bf16* __restrict__ aH, __bf16* __restrict__ aL) {
    int i = blockIdx.x * 256 + threadIdx.x;       // float4 idx over [2048][512]
    float4 a = ((const float4*)o0)[i];
    float4 c = ((const float4*)o1)[i];
    float4 d = ((const float4*)o2)[i];
    int m = i >> 9;
    int h = (i >> 6) & 7;
    int b = m >> 10, s = m & 1023;
    size_t li = (size_t)(b * H_ + h) * 1024 + s;
    float inv = 1.0f / (l0[li] + l1[li] + l2[li]);
    float o[4] = {(a.x + c.x + d.x) * inv, (a.y + c.y + d.y) * inv,
                  (a.z + c.z + d.z) * inv, (a.w + c.w + d.w) * inv};
    U4 ph, pl;
#pragma unroll
    for (int r = 0; r < 4; ++r) {
        __bf16 hi = (__bf16)o[r];
        ph.b[r] = hi;
        pl.b[r] = (__bf16)(o[r] - (float)hi);
    }
    *(unsigned long long*)&aH[(size_t)i * 4] = ph.u;
    *(unsigned long long*)&aL[(size_t)i * 4] = pl.u;
}

extern "C" void kernel_launch(void* const* d_in, const int* in_sizes, int n_in,
                              void* d_out, int out_size, void* d_ws, size_t ws_size,
                              hipStream_t stream) {
    (void)in_sizes; (void)n_in; (void)out_size; (void)ws_size;
    const float* hs  = (const float*)d_in[0];
    const float* enc = (const float*)d_in[1];
    const float* cs  = (const float*)d_in[2];
    const float* sn  = (const float*)d_in[3];
    const float* wq  = (const float*)d_in[4];
    const float* wk  = (const float*)d_in[5];
    const float* wv  = (const float*)d_in[6];
    const float* wo  = (const float*)d_in[7];
    const float* qnw = (const float*)d_in[8];
    const float* knw = (const float*)d_in[9];
    const int* dm    = (const int*)d_in[10];
    const int* em    = (const int*)d_in[11];
    const int* pos   = (const int*)d_in[12];
    float* out = (float*)d_out;

    char* ws = (char*)d_ws;
    const size_t MB = 1ull << 20;
    __bf16* hs_bf   = (__bf16*)(ws + 0 * MB);    // 8 MB   (dead after gemm_proj)
    __bf16* enc_bf  = (__bf16*)(ws + 8 * MB);    // 8 MB   (dead after gemm_proj)
    __bf16* wqkvTH  = (__bf16*)(ws + 16 * MB);   // 16 MB  (dead after gemm_proj)
    __bf16* wqkvTL  = (__bf16*)(ws + 32 * MB);   // 16 MB  (dead after gemm_proj)
    __bf16* woTH    = (__bf16*)(ws + 48 * MB);   // 8 MB
    __bf16* woTL    = (__bf16*)(ws + 56 * MB);   // 8 MB
    float*  qf32    = (float*)(ws + 64 * MB);    // 16 MB  (dead after rmsnorm q)
    float*  ksf     = (float*)(ws + 80 * MB);    // 8 MB   (dead after rmsnorm k)
    float*  kcf     = (float*)(ws + 88 * MB);    // 8 MB   (dead after rmsnorm kc)
    __bf16* k_bf    = (__bf16*)(ws + 104 * MB);  // 4 MB   [B][KV][S][256]
    __bf16* kc_bf   = (__bf16*)(ws + 108 * MB);  // 4 MB
    __bf16* vtS     = (__bf16*)(ws + 112 * MB);  // 4 MB   [B][KV][256][S]
    __bf16* vtC     = (__bf16*)(ws + 116 * MB);  // 4 MB
    int*    seg     = (int*)(ws + 120 * MB);     // 8 KB
    int*    kinfo   = (int*)(ws + 121 * MB);     // 16 KB
    float*  l0      = (float*)(ws + 122 * MB);            // 64 KB each
    float*  l1      = (float*)(ws + 122 * MB + 65536);
    float*  l2      = (float*)(ws + 122 * MB + 131072);
    __bf16* q_bf    = (__bf16*)(ws + 124 * MB);  // 8 MB   [B][S][H][256]
    // reuse of dead regions (live only between attn_part and merge/gemm_out):
    float*  o0      = (float*)(ws + 64 * MB);        // 16.78 MB over qf32+ksf head
    float*  o1      = (float*)(ws + 81 * MB);        // 16.78 MB over ksf tail+kcf+96..97.8
    float*  o2      = (float*)(ws + 17 * MB + 524288); // 16.78 MB over wqkvTH tail+wqkvTL head
    __bf16* aoutH   = (__bf16*)(ws + 0 * MB);        // 8.39 MB over hs_bf
    __bf16* aoutL   = (__bf16*)(ws + 9 * MB);        // 8.39 MB over enc_bf+wqkvTH head

    const int M = B_ * S_;   // 2048

    tobf16<<<4096, 256, 0, stream>>>(hs, hs_bf, M * D_ / 4);
    tobf16<<<4096, 256, 0, stream>>>(enc, enc_bf, M * D_ / 4);
    tsplit<<<dim3(64, 64), 256, 0, stream>>>(wq, wqkvTH, wqkvTL, D_, 2048);
    tsplit<<<dim3(64, 32), 256, 0, stream>>>(wk, wqkvTH + (size_t)2048 * 2048,
                                             wqkvTL + (size_t)2048 * 2048, D_, 1024);
    tsplit<<<dim3(64, 32), 256, 0, stream>>>(wv, wqkvTH + (size_t)3072 * 2048,
                                             wqkvTL + (size_t)3072 * 2048, D_, 1024);
    tsplit<<<dim3(64, 64), 256, 0, stream>>>(wo, woTH, woTL, 2048, D_);

    gemm_proj<<<dim3(48, 16), 256, 0, stream>>>(hs_bf, enc_bf, wqkvTH, wqkvTL,
                                                qf32, ksf, kcf, vtS, vtC);

    rmsnorm_rope<<<16384, 256, 0, stream>>>(qf32, q_bf, qnw, cs, sn, H_, 1, 0);
    rmsnorm_rope<<<8192, 256, 0, stream>>>(ksf, k_bf, knw, cs, sn, KV_, 1, 1);
    rmsnorm_rope<<<8192, 256, 0, stream>>>(kcf, kc_bf, knw, cs, sn, KV_, 0, 1);
    segscan<<<B_, 1024, 0, stream>>>(pos, dm, em, seg, kinfo);

    attn_part<<<3072, 64, 0, stream>>>(q_bf, k_bf, kc_bf, vtS, vtC, seg, kinfo,
                                       o0, o1, o2, l0, l1, l2);
    merge_attn<<<4096, 256, 0, stream>>>(o0, o1, o2, l0, l1, l2, aoutH, aoutL);

    gemm_out<<<dim3(16, 16), 256, 0, stream>>>(aoutH, aoutL, woTH, woTL, out);
}

// Round 6
// 498.014 us; speedup vs baseline: 4.8567x; 1.2540x over previous
//
#include <hip/hip_runtime.h>
#include <math.h>

#define B_ 2
#define S_ 1024
#define E_ 1024
#define D_ 2048
#define H_ 8
#define KV_ 4
#define HD_ 256
#define WINDOW_ 512u
#define SCALE_ 0.0625f
#define CAP_ 50.0f
#define EPS_ 1e-6f
#define CROSS_OK (-7)
#define KINV (-2147483647 - 1)

typedef __bf16 bf8_t __attribute__((ext_vector_type(8)));
typedef float fx4 __attribute__((ext_vector_type(4)));
#define MFMA16(a, b, c) __builtin_amdgcn_mfma_f32_16x16x32_bf16((a), (b), (c), 0, 0, 0)

typedef __attribute__((address_space(1))) unsigned int gas_u32;
typedef __attribute__((address_space(3))) unsigned int las_u32;
__device__ __forceinline__ void gl2lds16(const void* g, void* l) {
    __builtin_amdgcn_global_load_lds((const gas_u32*)g, (las_u32*)l, 16, 0, 0);
}

union U4 { __bf16 b[4]; unsigned long long u; };

// p = exp(50*tanh(dot*SCALE/50) - 50) = exp(-100/(exp(dot*2*SCALE/50)+1))
__device__ __forceinline__ float pexp(float dot) {
    float e = __expf(dot * (2.0f * SCALE_ / CAP_));
    return __expf(-(2.0f * CAP_) / (e + 1.0f));
}

// ---------------- fp32 -> bf16 (hi only) ----------------
__global__ __launch_bounds__(256) void tobf16(const float* __restrict__ x,
                                              __bf16* __restrict__ y, int n4) {
    int i = blockIdx.x * 256 + threadIdx.x;
    if (i >= n4) return;
    float4 v = ((const float4*)x)[i];
    U4 p;
    p.b[0] = (__bf16)v.x; p.b[1] = (__bf16)v.y;
    p.b[2] = (__bf16)v.z; p.b[3] = (__bf16)v.w;
    *(unsigned long long*)&y[(size_t)i * 4] = p.u;
}

// ---------------- transpose + split: W (KxN fp32) -> WT hi/lo (NxK bf16) -----
__global__ __launch_bounds__(256) void tsplit(const float* __restrict__ W,
                                              __bf16* __restrict__ Th,
                                              __bf16* __restrict__ Tl, int K, int N) {
    __shared__ float tile[32][33];
    const int t = threadIdx.x, tx = t & 31, ty = t >> 5;
    const int k0 = blockIdx.x * 32, n0 = blockIdx.y * 32;
#pragma unroll
    for (int r = 0; r < 4; ++r)
        tile[ty + r * 8][tx] = W[(size_t)(k0 + ty + r * 8) * N + n0 + tx];
    __syncthreads();
#pragma unroll
    for (int r = 0; r < 4; ++r) {
        float v = tile[tx][ty + r * 8];
        __bf16 h = (__bf16)v;
        size_t o = (size_t)(n0 + ty + r * 8) * K + k0 + tx;
        Th[o] = h;
        Tl[o] = (__bf16)(v - (float)h);
    }
}

// ---------------- shared GEMM core: 128x128 tile, BK=32, gl2lds staging ------
template <int NPASS>
__device__ __forceinline__ void gemm_core(
    const __bf16* __restrict__ Ah, const __bf16* __restrict__ Al,
    const __bf16* __restrict__ Bh, const __bf16* __restrict__ Bl,
    int row0, int col0, int K,
    __bf16* As0, __bf16* As1, __bf16* Bs0, __bf16* Bs1, fx4 (&acc)[4][4]) {
    const int tid = threadIdx.x, lane = tid & 63, wv = tid >> 6;
    const int l15 = lane & 15, lq = lane >> 4;
    const int wm = (wv >> 1) * 64, wn = (wv & 1) * 64;
    for (int k0 = 0; k0 < K; k0 += 32) {
        __syncthreads();
#pragma unroll
        for (int s = 0; s < 2; ++s) {
            int ch = (wv * 2 + s) * 64 + lane;       // 0..511
            int r = ch >> 2, kc = ch & 3;
            size_t ga = (size_t)(row0 + r) * K + k0 + kc * 8;
            size_t gb = (size_t)(col0 + r) * K + k0 + kc * 8;
            gl2lds16(Ah + ga, As0 + ch * 8);
            if (NPASS == 3) gl2lds16(Al + ga, As1 + ch * 8);
            gl2lds16(Bh + gb, Bs0 + ch * 8);
            gl2lds16(Bl + gb, Bs1 + ch * 8);
        }
        __syncthreads();
        bf8_t ah[4], al[4], bh[4], bl[4];
#pragma unroll
        for (int i = 0; i < 4; ++i) {
            int off = (wm + i * 16 + l15) * 32 + lq * 8;
            ah[i] = *(const bf8_t*)(As0 + off);
            if (NPASS == 3) al[i] = *(const bf8_t*)(As1 + off);
        }
#pragma unroll
        for (int j = 0; j < 4; ++j) {
            int off = (wn + j * 16 + l15) * 32 + lq * 8;
            bh[j] = *(const bf8_t*)(Bs0 + off);
            bl[j] = *(const bf8_t*)(Bs1 + off);
        }
#pragma unroll
        for (int i = 0; i < 4; ++i)
#pragma unroll
            for (int j = 0; j < 4; ++j) {
                acc[i][j] = MFMA16(ah[i], bh[j], acc[i][j]);
                acc[i][j] = MFMA16(ah[i], bl[j], acc[i][j]);
                if (NPASS == 3) acc[i][j] = MFMA16(al[i], bh[j], acc[i][j]);
            }
    }
}

// ---------------- fused projection GEMM (hs->q,k,v ; enc->kc,vc) ------------
__global__ __launch_bounds__(256) void gemm_proj(
    const __bf16* __restrict__ hsb, const __bf16* __restrict__ encb,
    const __bf16* __restrict__ BTh, const __bf16* __restrict__ BTl,
    float* __restrict__ qf32, float* __restrict__ ksf, float* __restrict__ kcf,
    __bf16* __restrict__ vtS, __bf16* __restrict__ vtC) {
    __shared__ __bf16 As0[4096], Bs0[4096], Bs1[4096];
    const int bx = blockIdx.x, row0 = blockIdx.y * 128;
    const __bf16* A;
    float* Ck; __bf16* Cv; int col0;
    if (bx < 32) { A = hsb;  col0 = bx * 128;               Ck = ksf; Cv = vtS; }
    else         { A = encb; col0 = (bx - 32) * 128 + 2048; Ck = kcf; Cv = vtC; }
    fx4 acc[4][4];
#pragma unroll
    for (int i = 0; i < 4; ++i)
#pragma unroll
        for (int j = 0; j < 4; ++j) acc[i][j] = (fx4){0.f, 0.f, 0.f, 0.f};
    gemm_core<2>(A, nullptr, BTh, BTl, row0, col0, D_, As0, nullptr, Bs0, Bs1, acc);

    const int tid = threadIdx.x, lane = tid & 63, wv = tid >> 6;
    const int l15 = lane & 15, lq = lane >> 4;
    const int wm = (wv >> 1) * 64, wn = (wv & 1) * 64;
    const int mode = (col0 < 2048) ? 0 : (col0 < 3072 ? 1 : 2);
#pragma unroll
    for (int i = 0; i < 4; ++i)
#pragma unroll
        for (int j = 0; j < 4; ++j) {
            int mb = row0 + wm + i * 16 + lq * 4;
            int n = col0 + wn + j * 16 + l15;
            if (mode == 0) {
#pragma unroll
                for (int r = 0; r < 4; ++r)
                    qf32[(size_t)(mb + r) * 2048 + n] = acc[i][j][r];
            } else if (mode == 1) {
                int nk = n - 2048;
#pragma unroll
                for (int r = 0; r < 4; ++r)
                    Ck[(size_t)(mb + r) * 1024 + nk] = acc[i][j][r];
            } else {
                int nv = n - 3072;
                int b = mb >> 10, s = mb & 1023;
                int kv = nv >> 8, d = nv & 255;
                U4 pk;
#pragma unroll
                for (int r = 0; r < 4; ++r) pk.b[r] = (__bf16)acc[i][j][r];
                *(unsigned long long*)&Cv[((size_t)(b * KV_ + kv) * HD_ + d) * 1024 + s] = pk.u;
            }
        }
}

// ---------------- output GEMM (3-term split) ----------------
__global__ __launch_bounds__(256) void gemm_out(
    const __bf16* __restrict__ Ah, const __bf16* __restrict__ Al,
    const __bf16* __restrict__ Bh, const __bf16* __restrict__ Bl,
    float* __restrict__ C) {
    __shared__ __bf16 As0[4096], As1[4096], Bs0[4096], Bs1[4096];
    const int row0 = blockIdx.y * 128, col0 = blockIdx.x * 128;
    fx4 acc[4][4];
#pragma unroll
    for (int i = 0; i < 4; ++i)
#pragma unroll
        for (int j = 0; j < 4; ++j) acc[i][j] = (fx4){0.f, 0.f, 0.f, 0.f};
    gemm_core<3>(Ah, Al, Bh, Bl, row0, col0, 2048, As0, As1, Bs0, Bs1, acc);
    const int tid = threadIdx.x, lane = tid & 63, wv = tid >> 6;
    const int l15 = lane & 15, lq = lane >> 4;
    const int wm = (wv >> 1) * 64, wn = (wv & 1) * 64;
#pragma unroll
    for (int i = 0; i < 4; ++i)
#pragma unroll
        for (int j = 0; j < 4; ++j) {
            int mb = row0 + wm + i * 16 + lq * 4;
            int n = col0 + wn + j * 16 + l15;
#pragma unroll
            for (int r = 0; r < 4; ++r)
                C[(size_t)(mb + r) * 2048 + n] = acc[i][j][r];
        }
}

// ---------------- RMSNorm (+optional RoPE): fp32 in, bf16 out ---------------
__global__ __launch_bounds__(256) void rmsnorm_rope(const float* __restrict__ x,
                                                    __bf16* __restrict__ out,
                                                    const float* __restrict__ w,
                                                    const float* __restrict__ cs,
                                                    const float* __restrict__ sn,
                                                    int nheads, int do_rope, int trans) {
    const int tid = threadIdx.x;
    const size_t base = (size_t)blockIdx.x * HD_;
    float v = x[base + tid];
    float ss = v * v;
#pragma unroll
    for (int off = 32; off; off >>= 1) ss += __shfl_down(ss, off);
    __shared__ float red[4];
    __shared__ float ybuf[HD_];
    const int lane = tid & 63, wvi = tid >> 6;
    if (lane == 0) red[wvi] = ss;
    __syncthreads();
    float tot = red[0] + red[1] + red[2] + red[3];
    float scale = rsqrtf(tot * (1.0f / HD_) + EPS_);
    float y = v * scale * (1.0f + w[tid]);
    const int m = blockIdx.x / nheads;
    if (do_rope) {
        ybuf[tid] = y;
        __syncthreads();
        float rot = (tid < HD_ / 2) ? -ybuf[tid + HD_ / 2] : ybuf[tid - HD_ / 2];
        size_t coff = (size_t)m * HD_;
        y = y * cs[coff + tid] + rot * sn[coff + tid];
    }
    size_t oidx;
    if (trans) {
        int hh = blockIdx.x % nheads;
        int b = m >> 10, s = m & 1023;
        oidx = ((size_t)(b * nheads + hh) * 1024 + s) * HD_ + tid;
    } else {
        oidx = base + tid;
    }
    out[oidx] = (__bf16)y;
}

// ---------------- segment scan + key info ----------------
__global__ void segscan(const int* __restrict__ pos, const int* __restrict__ dm,
                        const int* __restrict__ em, int* __restrict__ seg,
                        int* __restrict__ ki) {
    const int b = blockIdx.x, s = threadIdx.x;
    __shared__ int sh[1024];
    int p = pos[b * S_ + s];
    int r = (s == 0) ? 1 : (p <= pos[b * S_ + s - 1] ? 1 : 0);
    sh[s] = r;
    __syncthreads();
    for (int off = 1; off < 1024; off <<= 1) {
        int v = sh[s];
        int u = (s >= off) ? sh[s - off] : 0;
        __syncthreads();
        sh[s] = v + u;
        __syncthreads();
    }
    int sv = sh[s];
    seg[b * S_ + s] = sv;
    ki[b * 2048 + s] = dm[b * S_ + s] ? sv : KINV;
    ki[b * 2048 + 1024 + s] = em[b * E_ + s] ? CROSS_OK : KINV;
}

// ---------------- fused attention: 32 q-rows/block, LDS K/V, dbuf prefetch --
// 512 blocks (2/CU), 128 thr (2 waves). XOR-swizzled LDS layout keeps
// gl2lds16's lane-contiguous contract AND conflict-free ds_read_b128 frags.
// Raw s_waitcnt vmcnt(16)+s_barrier: tile t+1's 16 staging issues stay in
// flight across the barrier (never vmcnt(0) mid-loop). No partials.
__global__ __launch_bounds__(128, 1) void attn_fused(
    const __bf16* __restrict__ qb,   // [B][S][H][256]
    const __bf16* __restrict__ kb,   // [B][KV][S][256]
    const __bf16* __restrict__ kcb,  // [B][KV][E][256]
    const __bf16* __restrict__ vtS,  // [B][KV][256][S]
    const __bf16* __restrict__ vtC,  // [B][KV][256][E]
    const int* __restrict__ seg, const int* __restrict__ ki,
    __bf16* __restrict__ aH, __bf16* __restrict__ aL) {
    __shared__ __bf16 Ks[2][8192];   // [key 0..31][dchunk 0..31 ^ (key&7)] x16B
    __shared__ __bf16 Vs[2][8192];   // [d 0..255][kc 0..3 ^ ((d>>1)&3)] x16B
    __shared__ __bf16 Ps[2][640];    // per-wave P, row stride 40
    __shared__ int kinfoS[1600];
    const int tid = threadIdx.x, lane = tid & 63, wv = tid >> 6;
    const int l15 = lane & 15, lq = lane >> 4;
    const int g = blockIdx.x & 7;              // XCD-affine: one (b,kv) per XCD
    const int b = g >> 2, kv = g & 3;
    const int rest = blockIdx.x >> 3;          // 0..63
    const int qt = rest >> 1, h = kv * 2 + (rest & 1);
    const int s0 = qt * 32;
    const int lo = (s0 >= 512) ? ((s0 - 511) & ~31) : 0;
    const int nself = (s0 + 32 - lo) >> 5;
    const int nselfK = nself * 32;
    const int nt = nself + 32;

    for (int i = tid; i < nselfK + 1024; i += 128)     // stage kinfo once
        kinfoS[i] = (i < nselfK) ? ki[b * 2048 + lo + i]
                                 : ki[b * 2048 + 1024 + (i - nselfK)];
    __syncthreads();

    const int qpos = s0 + wv * 16 + l15;
    bf8_t qf[8];
    const __bf16* qrow = qb + ((size_t)(b * S_ + qpos) * H_ + h) * HD_;
#pragma unroll
    for (int f = 0; f < 8; ++f) qf[f] = *(const bf8_t*)(qrow + f * 32 + lq * 8);
    const int segq = seg[b * S_ + qpos];

    const __bf16* KbS = kb  + (size_t)(b * KV_ + kv) * (1024 * 256);
    const __bf16* VbS = vtS + (size_t)(b * KV_ + kv) * (256 * 1024);
    const __bf16* KbC = kcb + (size_t)(b * KV_ + kv) * (1024 * 256);
    const __bf16* VbC = vtC + (size_t)(b * KV_ + kv) * (256 * 1024);

    const __bf16 *Kt, *Vt; int kio, kt0, sf;
    auto tinfo = [&](int i) {
        if (i < nself) { sf = 1; kt0 = lo + i * 32;
                         Kt = KbS + (size_t)kt0 * 256; Vt = VbS + kt0; kio = i * 32; }
        else { sf = 0; int j = i - nself; kt0 = j * 32;
               Kt = KbC + (size_t)kt0 * 256; Vt = VbC + kt0; kio = nselfK + j * 32; }
    };
    auto stage = [&](int buf) {
#pragma unroll
        for (int r = 0; r < 8; ++r) {
            int cid = r * 128 + tid;                     // 0..1023
            int key = cid >> 5, c = cid & 31;
            gl2lds16(Kt + key * 256 + (((c ^ (key & 7))) << 3), &Ks[buf][cid * 8]);
        }
#pragma unroll
        for (int r = 0; r < 8; ++r) {
            int cid = r * 128 + tid;
            int d = cid >> 2, kc = cid & 3;
            gl2lds16(Vt + (size_t)d * 1024 + ((kc ^ ((d >> 1) & 3)) << 3), &Vs[buf][cid * 8]);
        }
    };

    fx4 accO[16];
#pragma unroll
    for (int j = 0; j < 16; ++j) accO[j] = (fx4){0.f, 0.f, 0.f, 0.f};
    float lsum = 0.f;
    const int swzk = l15 & 7;
    const int swzv = lq ^ ((l15 >> 1) & 3);

    tinfo(0);
    stage(0);
    for (int i = 0; i < nt; ++i) {
        const int kio_c = kio, kt0_c = kt0, sf_c = sf;
        const int hasnext = (i + 1 < nt);
        if (hasnext) { tinfo(i + 1); stage((i + 1) & 1); }
        if (hasnext) __builtin_amdgcn_s_waitcnt(0x4F70);   // vmcnt(16): tile i done
        else         __builtin_amdgcn_s_waitcnt(0x0F70);   // vmcnt(0)
        __builtin_amdgcn_s_barrier();
        __builtin_amdgcn_sched_barrier(0);

        const __bf16* Ksb = Ks[i & 1];
        const __bf16* Vsb = Vs[i & 1];
        fx4 sc0 = (fx4){0.f, 0.f, 0.f, 0.f}, sc1 = (fx4){0.f, 0.f, 0.f, 0.f};
#pragma unroll
        for (int f = 0; f < 8; ++f) {
            bf8_t k0 = *(const bf8_t*)&Ksb[(l15 * 32 + ((f * 4 + lq) ^ swzk)) * 8];
            bf8_t k1 = *(const bf8_t*)&Ksb[((16 + l15) * 32 + ((f * 4 + lq) ^ swzk)) * 8];
            sc0 = MFMA16(k0, qf[f], sc0);
            sc1 = MFMA16(k1, qf[f], sc1);
        }
        int4 ki0 = *(const int4*)&kinfoS[kio_c + lq * 4];
        int4 ki1 = *(const int4*)&kinfoS[kio_c + 16 + lq * 4];
        int ka0[4] = {ki0.x, ki0.y, ki0.z, ki0.w};
        int ka1[4] = {ki1.x, ki1.y, ki1.z, ki1.w};
        const int tgt = sf_c ? segq : CROSS_OK;
        U4 p0, p1;
#pragma unroll
        for (int r = 0; r < 4; ++r) {
            int key0 = kt0_c + lq * 4 + r;
            float e0 = pexp(sc0[r]);
            float e1 = pexp(sc1[r]);
            bool ok0 = (ka0[r] == tgt) && (!sf_c || (unsigned)(qpos - key0) < WINDOW_);
            bool ok1 = (ka1[r] == tgt) && (!sf_c || (unsigned)(qpos - key0 - 16) < WINDOW_);
            float v0 = ok0 ? e0 : 0.f;
            float v1 = ok1 ? e1 : 0.f;
            lsum += v0 + v1;
            p0.b[r] = (__bf16)v0;
            p1.b[r] = (__bf16)v1;
        }
        *(unsigned long long*)&Ps[wv][l15 * 40 + lq * 4] = p0.u;
        *(unsigned long long*)&Ps[wv][l15 * 40 + 16 + lq * 4] = p1.u;
        bf8_t pf = *(const bf8_t*)&Ps[wv][l15 * 40 + lq * 8];
#pragma unroll
        for (int j = 0; j < 16; ++j) {
            bf8_t vb = *(const bf8_t*)&Vsb[((j * 16 + l15) * 4 + swzv) * 8];
            accO[j] = MFMA16(pf, vb, accO[j]);
        }
        __builtin_amdgcn_sched_barrier(0);
        __builtin_amdgcn_s_barrier();          // protect buffer before re-stage
    }

    lsum += __shfl_xor(lsum, 16, 64);
    lsum += __shfl_xor(lsum, 32, 64);
    float inv[4];
#pragma unroll
    for (int r = 0; r < 4; ++r) inv[r] = 1.0f / __shfl(lsum, lq * 4 + r, 64);
#pragma unroll
    for (int j = 0; j < 16; ++j)
#pragma unroll
        for (int r = 0; r < 4; ++r) {
            float o = accO[j][r] * inv[r];
            size_t idx = (size_t)(b * S_ + s0 + wv * 16 + lq * 4 + r) * 2048 +
                         h * 256 + j * 16 + l15;
            __bf16 hi = (__bf16)o;
            aH[idx] = hi;
            aL[idx] = (__bf16)(o - (float)hi);
        }
}

extern "C" void kernel_launch(void* const* d_in, const int* in_sizes, int n_in,
                              void* d_out, int out_size, void* d_ws, size_t ws_size,
                              hipStream_t stream) {
    (void)in_sizes; (void)n_in; (void)out_size; (void)ws_size;
    const float* hs  = (const float*)d_in[0];
    const float* enc = (const float*)d_in[1];
    const float* cs  = (const float*)d_in[2];
    const float* sn  = (const float*)d_in[3];
    const float* wq  = (const float*)d_in[4];
    const float* wk  = (const float*)d_in[5];
    const float* wv  = (const float*)d_in[6];
    const float* wo  = (const float*)d_in[7];
    const float* qnw = (const float*)d_in[8];
    const float* knw = (const float*)d_in[9];
    const int* dm    = (const int*)d_in[10];
    const int* em    = (const int*)d_in[11];
    const int* pos   = (const int*)d_in[12];
    float* out = (float*)d_out;

    char* ws = (char*)d_ws;
    const size_t MB = 1ull << 20;
    __bf16* hs_bf   = (__bf16*)(ws + 0 * MB);    // 8 MB   (dead after gemm_proj)
    __bf16* enc_bf  = (__bf16*)(ws + 8 * MB);    // 8 MB   (dead after gemm_proj)
    __bf16* wqkvTH  = (__bf16*)(ws + 16 * MB);   // 16 MB  (dead after gemm_proj)
    __bf16* wqkvTL  = (__bf16*)(ws + 32 * MB);   // 16 MB  (dead after gemm_proj)
    __bf16* woTH    = (__bf16*)(ws + 48 * MB);   // 8 MB
    __bf16* woTL    = (__bf16*)(ws + 56 * MB);   // 8 MB
    float*  qf32    = (float*)(ws + 64 * MB);    // 16 MB  (dead after rmsnorm q)
    float*  ksf     = (float*)(ws + 80 * MB);    // 8 MB   (dead after rmsnorm k)
    float*  kcf     = (float*)(ws + 88 * MB);    // 8 MB   (dead after rmsnorm kc)
    __bf16* k_bf    = (__bf16*)(ws + 104 * MB);  // 4 MB   [B][KV][S][256]
    __bf16* kc_bf   = (__bf16*)(ws + 108 * MB);  // 4 MB
    __bf16* vtS     = (__bf16*)(ws + 112 * MB);  // 4 MB   [B][KV][256][S]
    __bf16* vtC     = (__bf16*)(ws + 116 * MB);  // 4 MB
    int*    seg     = (int*)(ws + 120 * MB);     // 8 KB
    int*    kinfo   = (int*)(ws + 121 * MB);     // 16 KB
    __bf16* q_bf    = (__bf16*)(ws + 124 * MB);  // 8 MB   [B][S][H][256]
    // reuse of dead regions:
    __bf16* aoutH   = (__bf16*)(ws + 0 * MB);    // 8.39 MB over hs_bf
    __bf16* aoutL   = (__bf16*)(ws + 9 * MB);    // 8.39 MB over enc_bf+wqkvTH head

    const int M = B_ * S_;   // 2048

    tobf16<<<4096, 256, 0, stream>>>(hs, hs_bf, M * D_ / 4);
    tobf16<<<4096, 256, 0, stream>>>(enc, enc_bf, M * D_ / 4);
    tsplit<<<dim3(64, 64), 256, 0, stream>>>(wq, wqkvTH, wqkvTL, D_, 2048);
    tsplit<<<dim3(64, 32), 256, 0, stream>>>(wk, wqkvTH + (size_t)2048 * 2048,
                                             wqkvTL + (size_t)2048 * 2048, D_, 1024);
    tsplit<<<dim3(64, 32), 256, 0, stream>>>(wv, wqkvTH + (size_t)3072 * 2048,
                                             wqkvTL + (size_t)3072 * 2048, D_, 1024);
    tsplit<<<dim3(64, 64), 256, 0, stream>>>(wo, woTH, woTL, 2048, D_);

    gemm_proj<<<dim3(48, 16), 256, 0, stream>>>(hs_bf, enc_bf, wqkvTH, wqkvTL,
                                                qf32, ksf, kcf, vtS, vtC);

    rmsnorm_rope<<<16384, 256, 0, stream>>>(qf32, q_bf, qnw, cs, sn, H_, 1, 0);
    rmsnorm_rope<<<8192, 256, 0, stream>>>(ksf, k_bf, knw, cs, sn, KV_, 1, 1);
    rmsnorm_rope<<<8192, 256, 0, stream>>>(kcf, kc_bf, knw, cs, sn, KV_, 0, 1);
    segscan<<<B_, 1024, 0, stream>>>(pos, dm, em, seg, kinfo);

    attn_fused<<<512, 128, 0, stream>>>(q_bf, k_bf, kc_bf, vtS, vtC, seg, kinfo,
                                        aoutH, aoutL);

    gemm_out<<<dim3(16, 16), 256, 0, stream>>>(aoutH, aoutL, woTH, woTL, out);
}

// Round 7
// 448.399 us; speedup vs baseline: 5.3941x; 1.1106x over previous
//
#include <hip/hip_runtime.h>
#include <math.h>

#define B_ 2
#define S_ 1024
#define E_ 1024
#define D_ 2048
#define H_ 8
#define KV_ 4
#define HD_ 256
#define WINDOW_ 512u
#define SCALE_ 0.0625f
#define CAP_ 50.0f
#define EPS_ 1e-6f
#define CROSS_OK (-7)
#define KINV (-2147483647 - 1)

typedef __bf16 bf8_t __attribute__((ext_vector_type(8)));
typedef float fx4 __attribute__((ext_vector_type(4)));
#define MFMA16(a, b, c) __builtin_amdgcn_mfma_f32_16x16x32_bf16((a), (b), (c), 0, 0, 0)

typedef __attribute__((address_space(1))) unsigned int gas_u32;
typedef __attribute__((address_space(3))) unsigned int las_u32;
__device__ __forceinline__ void gl2lds16(const void* g, void* l) {
    __builtin_amdgcn_global_load_lds((const gas_u32*)g, (las_u32*)l, 16, 0, 0);
}

union U4 { __bf16 b[4]; unsigned long long u; };

// p = exp(50*tanh(dot*SCALE/50) - 50) = exp(-100/(exp(dot*2*SCALE/50)+1))
__device__ __forceinline__ float pexp(float dot) {
    float e = __expf(dot * (2.0f * SCALE_ / CAP_));
    return __expf(-(2.0f * CAP_) / (e + 1.0f));
}

// ---------------- fp32 -> bf16 (hi only) ----------------
__global__ __launch_bounds__(256) void tobf16(const float* __restrict__ x,
                                              __bf16* __restrict__ y, int n4) {
    int i = blockIdx.x * 256 + threadIdx.x;
    if (i >= n4) return;
    float4 v = ((const float4*)x)[i];
    U4 p;
    p.b[0] = (__bf16)v.x; p.b[1] = (__bf16)v.y;
    p.b[2] = (__bf16)v.z; p.b[3] = (__bf16)v.w;
    *(unsigned long long*)&y[(size_t)i * 4] = p.u;
}

// ---------------- transpose + split: W (KxN fp32) -> WT hi/lo (NxK bf16) -----
__global__ __launch_bounds__(256) void tsplit(const float* __restrict__ W,
                                              __bf16* __restrict__ Th,
                                              __bf16* __restrict__ Tl, int K, int N) {
    __shared__ float tile[32][33];
    const int t = threadIdx.x, tx = t & 31, ty = t >> 5;
    const int k0 = blockIdx.x * 32, n0 = blockIdx.y * 32;
#pragma unroll
    for (int r = 0; r < 4; ++r)
        tile[ty + r * 8][tx] = W[(size_t)(k0 + ty + r * 8) * N + n0 + tx];
    __syncthreads();
#pragma unroll
    for (int r = 0; r < 4; ++r) {
        float v = tile[tx][ty + r * 8];
        __bf16 h = (__bf16)v;
        size_t o = (size_t)(n0 + ty + r * 8) * K + k0 + tx;
        Th[o] = h;
        Tl[o] = (__bf16)(v - (float)h);
    }
}

// ---- GEMM core v2: 128x128 tile, BK=32, dbuf LDS + vmcnt(N) + XOR swizzle ---
// NPASS: 1 = Ah*Bh; 2 = +Ah*Bl; 3 = +Al*Bh.
// LDS slot map: slot(r,c) = r*4 + ((c + (r>>1)) & 3)  (16B chunks, c=0..3).
// Staging is gl2lds lane-contiguous in physical slots; frag reads of chunk lq
// hit all 8 four-bank groups across 8 consecutive lanes (conflict-free min).
template <int NPASS>
__device__ __forceinline__ void gemm_core2(
    const __bf16* __restrict__ Ah, const __bf16* __restrict__ Al,
    const __bf16* __restrict__ Bh, const __bf16* __restrict__ Bl,
    int row0, int col0, int K,
    __bf16* As0, __bf16* As1, __bf16* Bs0, __bf16* Bs1, fx4 (&acc)[4][4]) {
    const int tid = threadIdx.x, lane = tid & 63, wv = tid >> 6;
    const int l15 = lane & 15, lq = lane >> 4;
    const int wm = (wv >> 1) * 64, wn = (wv & 1) * 64;
    constexpr int WCNT = (NPASS == 1) ? 0x0F74 : (NPASS == 2) ? 0x0F76 : 0x0F78;

    auto stage = [&](int buf, int k0) {
#pragma unroll
        for (int s = 0; s < 2; ++s) {
            int ch = (wv * 2 + s) * 64 + lane;        // physical slot 0..511
            int r = ch >> 2, cp = ch & 3;
            int cl = (cp - ((r >> 1) & 3)) & 3;       // logical k-chunk
            size_t ga = (size_t)(row0 + r) * K + k0 + cl * 8;
            size_t gb = (size_t)(col0 + r) * K + k0 + cl * 8;
            gl2lds16(Ah + ga, As0 + buf * 4096 + ch * 8);
            if (NPASS >= 3) gl2lds16(Al + ga, As1 + buf * 4096 + ch * 8);
            gl2lds16(Bh + gb, Bs0 + buf * 4096 + ch * 8);
            if (NPASS >= 2) gl2lds16(Bl + gb, Bs1 + buf * 4096 + ch * 8);
        }
    };

    stage(0, 0);
    for (int k0 = 0; k0 < K; k0 += 32) {
        const int buf = (k0 >> 5) & 1;
        const bool hasnext = (k0 + 32 < K);
        if (hasnext) stage(buf ^ 1, k0 + 32);
        if (hasnext) __builtin_amdgcn_s_waitcnt(WCNT);   // tile k0 landed; next in flight
        else         __builtin_amdgcn_s_waitcnt(0x0F70); // vmcnt(0)
        __builtin_amdgcn_s_barrier();
        __builtin_amdgcn_sched_barrier(0);

        const __bf16* A0 = As0 + buf * 4096;
        const __bf16* A1 = As1 + buf * 4096;
        const __bf16* B0 = Bs0 + buf * 4096;
        const __bf16* B1 = Bs1 + buf * 4096;
        bf8_t ah[4], al[4], bh[4], bl[4];
#pragma unroll
        for (int i = 0; i < 4; ++i) {
            int row = wm + i * 16 + l15;
            int sl = row * 4 + ((lq + (row >> 1)) & 3);
            ah[i] = *(const bf8_t*)(A0 + sl * 8);
            if (NPASS >= 3) al[i] = *(const bf8_t*)(A1 + sl * 8);
        }
#pragma unroll
        for (int j = 0; j < 4; ++j) {
            int row = wn + j * 16 + l15;
            int sl = row * 4 + ((lq + (row >> 1)) & 3);
            bh[j] = *(const bf8_t*)(B0 + sl * 8);
            if (NPASS >= 2) bl[j] = *(const bf8_t*)(B1 + sl * 8);
        }
#pragma unroll
        for (int i = 0; i < 4; ++i)
#pragma unroll
            for (int j = 0; j < 4; ++j) {
                acc[i][j] = MFMA16(ah[i], bh[j], acc[i][j]);
                if (NPASS >= 2) acc[i][j] = MFMA16(ah[i], bl[j], acc[i][j]);
                if (NPASS >= 3) acc[i][j] = MFMA16(al[i], bh[j], acc[i][j]);
            }
        __builtin_amdgcn_sched_barrier(0);
        __builtin_amdgcn_s_barrier();     // protect buf before re-stage next iter
    }
}

// ---------------- fused projection GEMM (hs->q,k,v ; enc->kc,vc) ------------
// q/k columns: 1-pass (RMSNorm right after absorbs bf16 weight quantization);
// v columns (col0 >= 3072): 2-pass hi+lo (unnormalized path).
__global__ __launch_bounds__(256) void gemm_proj(
    const __bf16* __restrict__ hsb, const __bf16* __restrict__ encb,
    const __bf16* __restrict__ BTh, const __bf16* __restrict__ BTl,
    float* __restrict__ qf32, float* __restrict__ ksf, float* __restrict__ kcf,
    __bf16* __restrict__ vtS, __bf16* __restrict__ vtC) {
    __shared__ __bf16 As0[8192], Bs0[8192], Bs1[8192];
    const int bx = blockIdx.x, row0 = blockIdx.y * 128;
    const __bf16* A;
    float* Ck; __bf16* Cv; int col0;
    if (bx < 32) { A = hsb;  col0 = bx * 128;               Ck = ksf; Cv = vtS; }
    else         { A = encb; col0 = (bx - 32) * 128 + 2048; Ck = kcf; Cv = vtC; }
    fx4 acc[4][4];
#pragma unroll
    for (int i = 0; i < 4; ++i)
#pragma unroll
        for (int j = 0; j < 4; ++j) acc[i][j] = (fx4){0.f, 0.f, 0.f, 0.f};
    if (col0 >= 3072)
        gemm_core2<2>(A, nullptr, BTh, BTl, row0, col0, D_, As0, nullptr, Bs0, Bs1, acc);
    else
        gemm_core2<1>(A, nullptr, BTh, BTl, row0, col0, D_, As0, nullptr, Bs0, Bs1, acc);

    const int tid = threadIdx.x, lane = tid & 63, wv = tid >> 6;
    const int l15 = lane & 15, lq = lane >> 4;
    const int wm = (wv >> 1) * 64, wn = (wv & 1) * 64;
    const int mode = (col0 < 2048) ? 0 : (col0 < 3072 ? 1 : 2);
#pragma unroll
    for (int i = 0; i < 4; ++i)
#pragma unroll
        for (int j = 0; j < 4; ++j) {
            int mb = row0 + wm + i * 16 + lq * 4;
            int n = col0 + wn + j * 16 + l15;
            if (mode == 0) {
#pragma unroll
                for (int r = 0; r < 4; ++r)
                    qf32[(size_t)(mb + r) * 2048 + n] = acc[i][j][r];
            } else if (mode == 1) {
                int nk = n - 2048;
#pragma unroll
                for (int r = 0; r < 4; ++r)
                    Ck[(size_t)(mb + r) * 1024 + nk] = acc[i][j][r];
            } else {
                int nv = n - 3072;
                int b = mb >> 10, s = mb & 1023;
                int kv = nv >> 8, d = nv & 255;
                U4 pk;
#pragma unroll
                for (int r = 0; r < 4; ++r) pk.b[r] = (__bf16)acc[i][j][r];
                *(unsigned long long*)&Cv[((size_t)(b * KV_ + kv) * HD_ + d) * 1024 + s] = pk.u;
            }
        }
}

// ---------------- output GEMM (3-term split) ----------------
__global__ __launch_bounds__(256) void gemm_out(
    const __bf16* __restrict__ Ah, const __bf16* __restrict__ Al,
    const __bf16* __restrict__ Bh, const __bf16* __restrict__ Bl,
    float* __restrict__ C) {
    __shared__ __bf16 As0[8192], As1[8192], Bs0[8192], Bs1[8192];
    const int row0 = blockIdx.y * 128, col0 = blockIdx.x * 128;
    fx4 acc[4][4];
#pragma unroll
    for (int i = 0; i < 4; ++i)
#pragma unroll
        for (int j = 0; j < 4; ++j) acc[i][j] = (fx4){0.f, 0.f, 0.f, 0.f};
    gemm_core2<3>(Ah, Al, Bh, Bl, row0, col0, 2048, As0, As1, Bs0, Bs1, acc);
    const int tid = threadIdx.x, lane = tid & 63, wv = tid >> 6;
    const int l15 = lane & 15, lq = lane >> 4;
    const int wm = (wv >> 1) * 64, wn = (wv & 1) * 64;
#pragma unroll
    for (int i = 0; i < 4; ++i)
#pragma unroll
        for (int j = 0; j < 4; ++j) {
            int mb = row0 + wm + i * 16 + lq * 4;
            int n = col0 + wn + j * 16 + l15;
#pragma unroll
            for (int r = 0; r < 4; ++r)
                C[(size_t)(mb + r) * 2048 + n] = acc[i][j][r];
        }
}

// ---------------- RMSNorm (+optional RoPE): fp32 in, bf16 out ---------------
__global__ __launch_bounds__(256) void rmsnorm_rope(const float* __restrict__ x,
                                                    __bf16* __restrict__ out,
                                                    const float* __restrict__ w,
                                                    const float* __restrict__ cs,
                                                    const float* __restrict__ sn,
                                                    int nheads, int do_rope, int trans) {
    const int tid = threadIdx.x;
    const size_t base = (size_t)blockIdx.x * HD_;
    float v = x[base + tid];
    float ss = v * v;
#pragma unroll
    for (int off = 32; off; off >>= 1) ss += __shfl_down(ss, off);
    __shared__ float red[4];
    __shared__ float ybuf[HD_];
    const int lane = tid & 63, wvi = tid >> 6;
    if (lane == 0) red[wvi] = ss;
    __syncthreads();
    float tot = red[0] + red[1] + red[2] + red[3];
    float scale = rsqrtf(tot * (1.0f / HD_) + EPS_);
    float y = v * scale * (1.0f + w[tid]);
    const int m = blockIdx.x / nheads;
    if (do_rope) {
        ybuf[tid] = y;
        __syncthreads();
        float rot = (tid < HD_ / 2) ? -ybuf[tid + HD_ / 2] : ybuf[tid - HD_ / 2];
        size_t coff = (size_t)m * HD_;
        y = y * cs[coff + tid] + rot * sn[coff + tid];
    }
    size_t oidx;
    if (trans) {
        int hh = blockIdx.x % nheads;
        int b = m >> 10, s = m & 1023;
        oidx = ((size_t)(b * nheads + hh) * 1024 + s) * HD_ + tid;
    } else {
        oidx = base + tid;
    }
    out[oidx] = (__bf16)y;
}

// ---------------- segment scan + key info ----------------
__global__ void segscan(const int* __restrict__ pos, const int* __restrict__ dm,
                        const int* __restrict__ em, int* __restrict__ seg,
                        int* __restrict__ ki) {
    const int b = blockIdx.x, s = threadIdx.x;
    __shared__ int sh[1024];
    int p = pos[b * S_ + s];
    int r = (s == 0) ? 1 : (p <= pos[b * S_ + s - 1] ? 1 : 0);
    sh[s] = r;
    __syncthreads();
    for (int off = 1; off < 1024; off <<= 1) {
        int v = sh[s];
        int u = (s >= off) ? sh[s - off] : 0;
        __syncthreads();
        sh[s] = v + u;
        __syncthreads();
    }
    int sv = sh[s];
    seg[b * S_ + s] = sv;
    ki[b * 2048 + s] = dm[b * S_ + s] ? sv : KINV;
    ki[b * 2048 + 1024 + s] = em[b * E_ + s] ? CROSS_OK : KINV;
}

// ---------------- fused attention: 32 q-rows/block, LDS K/V, dbuf prefetch --
__global__ __launch_bounds__(128, 1) void attn_fused(
    const __bf16* __restrict__ qb,   // [B][S][H][256]
    const __bf16* __restrict__ kb,   // [B][KV][S][256]
    const __bf16* __restrict__ kcb,  // [B][KV][E][256]
    const __bf16* __restrict__ vtS,  // [B][KV][256][S]
    const __bf16* __restrict__ vtC,  // [B][KV][256][E]
    const int* __restrict__ seg, const int* __restrict__ ki,
    __bf16* __restrict__ aH, __bf16* __restrict__ aL) {
    __shared__ __bf16 Ks[2][8192];   // [key 0..31][dchunk 0..31 ^ (key&7)] x16B
    __shared__ __bf16 Vs[2][8192];   // [d 0..255][kc 0..3 ^ ((d>>1)&3)] x16B
    __shared__ __bf16 Ps[2][640];    // per-wave P, row stride 40
    __shared__ int kinfoS[1600];
    const int tid = threadIdx.x, lane = tid & 63, wv = tid >> 6;
    const int l15 = lane & 15, lq = lane >> 4;
    const int g = blockIdx.x & 7;              // XCD-affine: one (b,kv) per XCD
    const int b = g >> 2, kv = g & 3;
    const int rest = blockIdx.x >> 3;          // 0..63
    const int qt = rest >> 1, h = kv * 2 + (rest & 1);
    const int s0 = qt * 32;
    const int lo = (s0 >= 512) ? ((s0 - 511) & ~31) : 0;
    const int nself = (s0 + 32 - lo) >> 5;
    const int nselfK = nself * 32;
    const int nt = nself + 32;

    for (int i = tid; i < nselfK + 1024; i += 128)     // stage kinfo once
        kinfoS[i] = (i < nselfK) ? ki[b * 2048 + lo + i]
                                 : ki[b * 2048 + 1024 + (i - nselfK)];
    __syncthreads();

    const int qpos = s0 + wv * 16 + l15;
    bf8_t qf[8];
    const __bf16* qrow = qb + ((size_t)(b * S_ + qpos) * H_ + h) * HD_;
#pragma unroll
    for (int f = 0; f < 8; ++f) qf[f] = *(const bf8_t*)(qrow + f * 32 + lq * 8);
    const int segq = seg[b * S_ + qpos];

    const __bf16* KbS = kb  + (size_t)(b * KV_ + kv) * (1024 * 256);
    const __bf16* VbS = vtS + (size_t)(b * KV_ + kv) * (256 * 1024);
    const __bf16* KbC = kcb + (size_t)(b * KV_ + kv) * (1024 * 256);
    const __bf16* VbC = vtC + (size_t)(b * KV_ + kv) * (256 * 1024);

    const __bf16 *Kt, *Vt; int kio, kt0, sf;
    auto tinfo = [&](int i) {
        if (i < nself) { sf = 1; kt0 = lo + i * 32;
                         Kt = KbS + (size_t)kt0 * 256; Vt = VbS + kt0; kio = i * 32; }
        else { sf = 0; int j = i - nself; kt0 = j * 32;
               Kt = KbC + (size_t)kt0 * 256; Vt = VbC + kt0; kio = nselfK + j * 32; }
    };
    auto stage = [&](int buf) {
#pragma unroll
        for (int r = 0; r < 8; ++r) {
            int cid = r * 128 + tid;                     // 0..1023
            int key = cid >> 5, c = cid & 31;
            gl2lds16(Kt + key * 256 + (((c ^ (key & 7))) << 3), &Ks[buf][cid * 8]);
        }
#pragma unroll
        for (int r = 0; r < 8; ++r) {
            int cid = r * 128 + tid;
            int d = cid >> 2, kc = cid & 3;
            gl2lds16(Vt + (size_t)d * 1024 + ((kc ^ ((d >> 1) & 3)) << 3), &Vs[buf][cid * 8]);
        }
    };

    fx4 accO[16];
#pragma unroll
    for (int j = 0; j < 16; ++j) accO[j] = (fx4){0.f, 0.f, 0.f, 0.f};
    float lsum = 0.f;
    const int swzk = l15 & 7;
    const int swzv = lq ^ ((l15 >> 1) & 3);

    tinfo(0);
    stage(0);
    for (int i = 0; i < nt; ++i) {
        const int kio_c = kio, kt0_c = kt0, sf_c = sf;
        const int hasnext = (i + 1 < nt);
        if (hasnext) { tinfo(i + 1); stage((i + 1) & 1); }
        if (hasnext) __builtin_amdgcn_s_waitcnt(0x4F70);   // vmcnt(16): tile i done
        else         __builtin_amdgcn_s_waitcnt(0x0F70);   // vmcnt(0)
        __builtin_amdgcn_s_barrier();
        __builtin_amdgcn_sched_barrier(0);

        const __bf16* Ksb = Ks[i & 1];
        const __bf16* Vsb = Vs[i & 1];
        fx4 sc0 = (fx4){0.f, 0.f, 0.f, 0.f}, sc1 = (fx4){0.f, 0.f, 0.f, 0.f};
#pragma unroll
        for (int f = 0; f < 8; ++f) {
            bf8_t k0 = *(const bf8_t*)&Ksb[(l15 * 32 + ((f * 4 + lq) ^ swzk)) * 8];
            bf8_t k1 = *(const bf8_t*)&Ksb[((16 + l15) * 32 + ((f * 4 + lq) ^ swzk)) * 8];
            sc0 = MFMA16(k0, qf[f], sc0);
            sc1 = MFMA16(k1, qf[f], sc1);
        }
        int4 ki0 = *(const int4*)&kinfoS[kio_c + lq * 4];
        int4 ki1 = *(const int4*)&kinfoS[kio_c + 16 + lq * 4];
        int ka0[4] = {ki0.x, ki0.y, ki0.z, ki0.w};
        int ka1[4] = {ki1.x, ki1.y, ki1.z, ki1.w};
        const int tgt = sf_c ? segq : CROSS_OK;
        U4 p0, p1;
#pragma unroll
        for (int r = 0; r < 4; ++r) {
            int key0 = kt0_c + lq * 4 + r;
            float e0 = pexp(sc0[r]);
            float e1 = pexp(sc1[r]);
            bool ok0 = (ka0[r] == tgt) && (!sf_c || (unsigned)(qpos - key0) < WINDOW_);
            bool ok1 = (ka1[r] == tgt) && (!sf_c || (unsigned)(qpos - key0 - 16) < WINDOW_);
            float v0 = ok0 ? e0 : 0.f;
            float v1 = ok1 ? e1 : 0.f;
            lsum += v0 + v1;
            p0.b[r] = (__bf16)v0;
            p1.b[r] = (__bf16)v1;
        }
        *(unsigned long long*)&Ps[wv][l15 * 40 + lq * 4] = p0.u;
        *(unsigned long long*)&Ps[wv][l15 * 40 + 16 + lq * 4] = p1.u;
        bf8_t pf = *(const bf8_t*)&Ps[wv][l15 * 40 + lq * 8];
#pragma unroll
        for (int j = 0; j < 16; ++j) {
            bf8_t vb = *(const bf8_t*)&Vsb[((j * 16 + l15) * 4 + swzv) * 8];
            accO[j] = MFMA16(pf, vb, accO[j]);
        }
        __builtin_amdgcn_sched_barrier(0);
        __builtin_amdgcn_s_barrier();          // protect buffer before re-stage
    }

    lsum += __shfl_xor(lsum, 16, 64);
    lsum += __shfl_xor(lsum, 32, 64);
    float inv[4];
#pragma unroll
    for (int r = 0; r < 4; ++r) inv[r] = 1.0f / __shfl(lsum, lq * 4 + r, 64);
#pragma unroll
    for (int j = 0; j < 16; ++j)
#pragma unroll
        for (int r = 0; r < 4; ++r) {
            float o = accO[j][r] * inv[r];
            size_t idx = (size_t)(b * S_ + s0 + wv * 16 + lq * 4 + r) * 2048 +
                         h * 256 + j * 16 + l15;
            __bf16 hi = (__bf16)o;
            aH[idx] = hi;
            aL[idx] = (__bf16)(o - (float)hi);
        }
}

extern "C" void kernel_launch(void* const* d_in, const int* in_sizes, int n_in,
                              void* d_out, int out_size, void* d_ws, size_t ws_size,
                              hipStream_t stream) {
    (void)in_sizes; (void)n_in; (void)out_size; (void)ws_size;
    const float* hs  = (const float*)d_in[0];
    const float* enc = (const float*)d_in[1];
    const float* cs  = (const float*)d_in[2];
    const float* sn  = (const float*)d_in[3];
    const float* wq  = (const float*)d_in[4];
    const float* wk  = (const float*)d_in[5];
    const float* wv  = (const float*)d_in[6];
    const float* wo  = (const float*)d_in[7];
    const float* qnw = (const float*)d_in[8];
    const float* knw = (const float*)d_in[9];
    const int* dm    = (const int*)d_in[10];
    const int* em    = (const int*)d_in[11];
    const int* pos   = (const int*)d_in[12];
    float* out = (float*)d_out;

    char* ws = (char*)d_ws;
    const size_t MB = 1ull << 20;
    __bf16* hs_bf   = (__bf16*)(ws + 0 * MB);    // 8 MB   (dead after gemm_proj)
    __bf16* enc_bf  = (__bf16*)(ws + 8 * MB);    // 8 MB   (dead after gemm_proj)
    __bf16* wqkvTH  = (__bf16*)(ws + 16 * MB);   // 16 MB  (dead after gemm_proj)
    __bf16* wqkvTL  = (__bf16*)(ws + 32 * MB);   // 16 MB  (dead after gemm_proj)
    __bf16* woTH    = (__bf16*)(ws + 48 * MB);   // 8 MB
    __bf16* woTL    = (__bf16*)(ws + 56 * MB);   // 8 MB
    float*  qf32    = (float*)(ws + 64 * MB);    // 16 MB  (dead after rmsnorm q)
    float*  ksf     = (float*)(ws + 80 * MB);    // 8 MB   (dead after rmsnorm k)
    float*  kcf     = (float*)(ws + 88 * MB);    // 8 MB   (dead after rmsnorm kc)
    __bf16* k_bf    = (__bf16*)(ws + 104 * MB);  // 4 MB   [B][KV][S][256]
    __bf16* kc_bf   = (__bf16*)(ws + 108 * MB);  // 4 MB
    __bf16* vtS     = (__bf16*)(ws + 112 * MB);  // 4 MB   [B][KV][256][S]
    __bf16* vtC     = (__bf16*)(ws + 116 * MB);  // 4 MB
    int*    seg     = (int*)(ws + 120 * MB);     // 8 KB
    int*    kinfo   = (int*)(ws + 121 * MB);     // 16 KB
    __bf16* q_bf    = (__bf16*)(ws + 124 * MB);  // 8 MB   [B][S][H][256]
    // reuse of dead regions:
    __bf16* aoutH   = (__bf16*)(ws + 0 * MB);    // 8.39 MB over hs_bf
    __bf16* aoutL   = (__bf16*)(ws + 9 * MB);    // 8.39 MB over enc_bf+wqkvTH head

    const int M = B_ * S_;   // 2048

    tobf16<<<4096, 256, 0, stream>>>(hs, hs_bf, M * D_ / 4);
    tobf16<<<4096, 256, 0, stream>>>(enc, enc_bf, M * D_ / 4);
    tsplit<<<dim3(64, 64), 256, 0, stream>>>(wq, wqkvTH, wqkvTL, D_, 2048);
    tsplit<<<dim3(64, 32), 256, 0, stream>>>(wk, wqkvTH + (size_t)2048 * 2048,
                                             wqkvTL + (size_t)2048 * 2048, D_, 1024);
    tsplit<<<dim3(64, 32), 256, 0, stream>>>(wv, wqkvTH + (size_t)3072 * 2048,
                                             wqkvTL + (size_t)3072 * 2048, D_, 1024);
    tsplit<<<dim3(64, 64), 256, 0, stream>>>(wo, woTH, woTL, 2048, D_);

    gemm_proj<<<dim3(48, 16), 256, 0, stream>>>(hs_bf, enc_bf, wqkvTH, wqkvTL,
                                                qf32, ksf, kcf, vtS, vtC);

    rmsnorm_rope<<<16384, 256, 0, stream>>>(qf32, q_bf, qnw, cs, sn, H_, 1, 0);
    rmsnorm_rope<<<8192, 256, 0, stream>>>(ksf, k_bf, knw, cs, sn, KV_, 1, 1);
    rmsnorm_rope<<<8192, 256, 0, stream>>>(kcf, kc_bf, knw, cs, sn, KV_, 0, 1);
    segscan<<<B_, 1024, 0, stream>>>(pos, dm, em, seg, kinfo);

    attn_fused<<<512, 128, 0, stream>>>(q_bf, k_bf, kc_bf, vtS, vtC, seg, kinfo,
                                        aoutH, aoutL);

    gemm_out<<<dim3(16, 16), 256, 0, stream>>>(aoutH, aoutL, woTH, woTL, out);
}